// Round 2
// baseline (1576.431 us; speedup 1.0000x reference)
//
#include <hip/hip_runtime.h>
#include <hip/hip_bf16.h>
#include <math.h>

// ---------------------------------------------------------------------------
// LinearAttention: B=16, DIM=256, H=W=64 (n=4096), HEADS=8, DH=64, INNER=512
// Round 2: fp32 baseline with SMALL workspace footprint.
//   - dw lives in d_out (64 MB, dead before final writes)
//   - kv never materialized (2-pass online k-softmax + fused context)
//   - q never materialized (fused q-GEMM + softmax + PV + GELU -> bf16 out2)
//   - out2 pixel-sliced to fit ws_size (min ~16.1 MB of d_ws needed)
// ---------------------------------------------------------------------------

static constexpr int NPIX = 4096;
typedef long long i64;

// ---------------- K1: depthwise 3x3, pad 1 (cross-correlation) -------------
__global__ __launch_bounds__(256) void dwconv_kernel(const float* __restrict__ fmap,
                                                     const float* __restrict__ Wdw,
                                                     float* __restrict__ dw) {
  i64 p = (i64)blockIdx.x * 256 + threadIdx.x;     // over 16*256*4096
  int y = (int)(p & 63);
  int x = (int)((p >> 6) & 63);
  int c = (int)((p >> 12) & 255);
  const float* img = fmap + (p >> 12) * (i64)NPIX;
  const float* w = Wdw + c * 9;
  float s = 0.f;
  #pragma unroll
  for (int dx = -1; dx <= 1; ++dx) {
    int xx = x + dx;
    if ((unsigned)xx < 64u) {
      #pragma unroll
      for (int dy = -1; dy <= 1; ++dy) {
        int yy = y + dy;
        if ((unsigned)yy < 64u)
          s = fmaf(w[(dx + 1) * 3 + (dy + 1)], img[xx * 64 + yy], s);
      }
    }
  }
  dw[p] = s;
}

// ---------------- K2: k-GEMM tile + online (max, sumexp) partials ----------
// block: (chunk of 128 px, ogroup of 64 k-ch, b). k = Wpw[0:512] @ dw.
__global__ __launch_bounds__(256) void kstats_kernel(const float* __restrict__ Wpw,
                                                     const float* __restrict__ dw,
                                                     float* __restrict__ partM,
                                                     float* __restrict__ partS) {
  __shared__ float Ws[16][68];
  __shared__ float Xs[16][128];
  const int chunk = blockIdx.x, og = blockIdx.y, b = blockIdx.z;
  const int i0 = chunk * 128;
  const int tid = threadIdx.x;
  const int to = tid >> 4, tn = tid & 15;
  const float* Wp = Wpw + (i64)(og * 64) * 256;
  const float* Xp = dw + (i64)b * 256 * NPIX;
  float acc[4][8];
  #pragma unroll
  for (int a = 0; a < 4; ++a)
    #pragma unroll
    for (int p = 0; p < 8; ++p) acc[a][p] = 0.f;

  for (int c0 = 0; c0 < 256; c0 += 16) {
    float4 wv  = *(const float4*)&Wp[(i64)(tid >> 2) * 256 + c0 + (tid & 3) * 4];
    float4 xv0 = *(const float4*)&Xp[(i64)(c0 + (tid >> 5)) * NPIX + i0 + (tid & 31) * 4];
    float4 xv1 = *(const float4*)&Xp[(i64)(c0 + 8 + (tid >> 5)) * NPIX + i0 + (tid & 31) * 4];
    __syncthreads();
    const int wr = (tid & 3) * 4, wc = tid >> 2;
    Ws[wr + 0][wc] = wv.x; Ws[wr + 1][wc] = wv.y; Ws[wr + 2][wc] = wv.z; Ws[wr + 3][wc] = wv.w;
    *(float4*)&Xs[tid >> 5][(tid & 31) * 4] = xv0;
    *(float4*)&Xs[8 + (tid >> 5)][(tid & 31) * 4] = xv1;
    __syncthreads();
    #pragma unroll
    for (int kc = 0; kc < 16; ++kc) {
      float4 w4 = *(const float4*)&Ws[kc][to * 4];
      float4 x0 = *(const float4*)&Xs[kc][tn * 4];
      float4 x1 = *(const float4*)&Xs[kc][64 + tn * 4];
      const float wa[4] = {w4.x, w4.y, w4.z, w4.w};
      const float xa[8] = {x0.x, x0.y, x0.z, x0.w, x1.x, x1.y, x1.z, x1.w};
      #pragma unroll
      for (int a = 0; a < 4; ++a)
        #pragma unroll
        for (int p = 0; p < 8; ++p)
          acc[a][p] = fmaf(wa[a], xa[p], acc[a][p]);
    }
  }
  // per-row (k channel) reduce over the 128-px chunk: 16 tn lanes share a row
  #pragma unroll
  for (int a = 0; a < 4; ++a) {
    float m = acc[a][0];
    #pragma unroll
    for (int p = 1; p < 8; ++p) m = fmaxf(m, acc[a][p]);
    m = fmaxf(m, __shfl_xor(m, 1));
    m = fmaxf(m, __shfl_xor(m, 2));
    m = fmaxf(m, __shfl_xor(m, 4));
    m = fmaxf(m, __shfl_xor(m, 8));
    float s = 0.f;
    #pragma unroll
    for (int p = 0; p < 8; ++p) s += expf(acc[a][p] - m);
    s += __shfl_xor(s, 1);
    s += __shfl_xor(s, 2);
    s += __shfl_xor(s, 4);
    s += __shfl_xor(s, 8);
    if (tn == 0) {
      int row = b * 512 + og * 64 + to * 4 + a;
      partM[(i64)row * 32 + chunk] = m;
      partS[(i64)row * 32 + chunk] = s;
    }
  }
}

// ---------------- K3: merge 32 chunk partials -> (M, 1/S) per row ----------
__global__ __launch_bounds__(256) void kstats_reduce_kernel(const float* __restrict__ partM,
                                                            const float* __restrict__ partS,
                                                            float* __restrict__ Mst,
                                                            float* __restrict__ Ist) {
  int r = blockIdx.x * 256 + threadIdx.x;          // 16*512 rows
  float M = -1e30f;
  #pragma unroll 4
  for (int c = 0; c < 32; ++c) M = fmaxf(M, partM[(i64)r * 32 + c]);
  float S = 0.f;
  #pragma unroll 4
  for (int c = 0; c < 32; ++c) S += partS[(i64)r * 32 + c] * expf(partM[(i64)r * 32 + c] - M);
  Mst[r] = M;
  Ist[r] = 1.0f / S;
}

// ---------------- K4: recompute k,v tiles; ctx_part = k_hat @ v^T ----------
// block: (chunk of 1024 px, head, b). 16 sub-tiles of 64 px each.
__global__ __launch_bounds__(256) void context_kernel(const float* __restrict__ Wpw,
                                                      const float* __restrict__ dw,
                                                      const float* __restrict__ Mst,
                                                      const float* __restrict__ Ist,
                                                      float* __restrict__ part) {
  __shared__ float Wsk[16][68], Wsv[16][68];
  __shared__ float Xs[16][64];
  __shared__ float kt[64][68], vt[64][68];         // [px][ch]
  const int chunk = blockIdx.x, h = blockIdx.y, b = blockIdx.z;
  const int tid = threadIdx.x;
  const int to = tid >> 4, tn = tid & 15;
  const float* Wk = Wpw + (i64)(h * 64) * 256;
  const float* Wv = Wpw + (i64)(512 + h * 64) * 256;
  const float* Xp = dw + (i64)b * 256 * NPIX;
  float Mreg[4], Ireg[4];
  #pragma unroll
  for (int a = 0; a < 4; ++a) {
    int row = b * 512 + h * 64 + to * 4 + a;
    Mreg[a] = Mst[row];
    Ireg[a] = Ist[row];
  }
  float acc2[4][4];
  #pragma unroll
  for (int a = 0; a < 4; ++a)
    #pragma unroll
    for (int e = 0; e < 4; ++e) acc2[a][e] = 0.f;

  for (int st = 0; st < 16; ++st) {
    const int px0 = chunk * 1024 + st * 64;
    float ak[4][4], av[4][4];
    #pragma unroll
    for (int a = 0; a < 4; ++a)
      #pragma unroll
      for (int p = 0; p < 4; ++p) { ak[a][p] = 0.f; av[a][p] = 0.f; }

    for (int c0 = 0; c0 < 256; c0 += 16) {
      float4 wk = *(const float4*)&Wk[(i64)(tid >> 2) * 256 + c0 + (tid & 3) * 4];
      float4 wv = *(const float4*)&Wv[(i64)(tid >> 2) * 256 + c0 + (tid & 3) * 4];
      float4 xv = *(const float4*)&Xp[(i64)(c0 + (tid >> 4)) * NPIX + px0 + (tid & 15) * 4];
      __syncthreads();                             // prev readers done (also guards kt/vt of prev st)
      const int wr = (tid & 3) * 4, wc = tid >> 2;
      Wsk[wr + 0][wc] = wk.x; Wsk[wr + 1][wc] = wk.y; Wsk[wr + 2][wc] = wk.z; Wsk[wr + 3][wc] = wk.w;
      Wsv[wr + 0][wc] = wv.x; Wsv[wr + 1][wc] = wv.y; Wsv[wr + 2][wc] = wv.z; Wsv[wr + 3][wc] = wv.w;
      *(float4*)&Xs[tid >> 4][(tid & 15) * 4] = xv;
      __syncthreads();
      #pragma unroll
      for (int kc = 0; kc < 16; ++kc) {
        float4 k4 = *(const float4*)&Wsk[kc][to * 4];
        float4 v4 = *(const float4*)&Wsv[kc][to * 4];
        float4 x4 = *(const float4*)&Xs[kc][tn * 4];
        const float ka[4] = {k4.x, k4.y, k4.z, k4.w};
        const float va[4] = {v4.x, v4.y, v4.z, v4.w};
        const float xa[4] = {x4.x, x4.y, x4.z, x4.w};
        #pragma unroll
        for (int a = 0; a < 4; ++a)
          #pragma unroll
          for (int p = 0; p < 4; ++p) {
            ak[a][p] = fmaf(ka[a], xa[p], ak[a][p]);
            av[a][p] = fmaf(va[a], xa[p], av[a][p]);
          }
      }
    }
    // apply token-softmax to k, write transposed tiles [px][ch]
    #pragma unroll
    for (int a = 0; a < 4; ++a)
      #pragma unroll
      for (int p = 0; p < 4; ++p) {
        kt[tn * 4 + p][to * 4 + a] = expf(ak[a][p] - Mreg[a]) * Ireg[a];
        vt[tn * 4 + p][to * 4 + a] = av[a][p];
      }
    __syncthreads();
    // outer-product accumulate: d-group = tn, e-group = to
    #pragma unroll 4
    for (int px = 0; px < 64; ++px) {
      float4 kk = *(const float4*)&kt[px][tn * 4];
      float4 vv = *(const float4*)&vt[px][to * 4];
      const float ka[4] = {kk.x, kk.y, kk.z, kk.w};
      const float va[4] = {vv.x, vv.y, vv.z, vv.w};
      #pragma unroll
      for (int a = 0; a < 4; ++a)
        #pragma unroll
        for (int e = 0; e < 4; ++e)
          acc2[a][e] = fmaf(ka[a], va[e], acc2[a][e]);
    }
    __syncthreads();
  }
  float* pb = part + (i64)((b * 8 + h) * 4 + chunk) * 4096;
  #pragma unroll
  for (int a = 0; a < 4; ++a)
    *(float4*)&pb[(tn * 4 + a) * 64 + to * 4] =
        make_float4(acc2[a][0], acc2[a][1], acc2[a][2], acc2[a][3]);
}

// ---------------- K5: reduce 4 chunk partials -> ctx[bh][d][e] -------------
__global__ __launch_bounds__(256) void ctx_reduce_kernel(const float* __restrict__ part,
                                                         float* __restrict__ ctx) {
  int i = blockIdx.x * 256 + threadIdx.x;          // 128*4096
  int bh = i >> 12, j = i & 4095;
  float s = 0.f;
  #pragma unroll
  for (int c = 0; c < 4; ++c) s += part[(i64)(bh * 4 + c) * 4096 + j];
  ctx[i] = s;
}

// ---------------- K6: fused q-GEMM + feature-softmax + PV + GELU -----------
// block: (px-tile of 128 within slice, head, b). out2 slice-local, bf16.
__global__ __launch_bounds__(256) void qpv_kernel(const float* __restrict__ Wq,
                                                  const float* __restrict__ fmap,
                                                  const float* __restrict__ ctx,
                                                  __hip_bfloat16* __restrict__ out2,
                                                  int pxbase, int NS) {
  __shared__ float Ws[16][68];
  __shared__ float Xs[16][128];
  __shared__ float qt[64][132];                    // [ch][px]
  __shared__ float cs[64][68];                     // [d][e]
  const int h = blockIdx.y, b = blockIdx.z;
  const int i0 = blockIdx.x * 128;                 // slice-local
  const int tid = threadIdx.x;
  const int to = tid >> 4, tn = tid & 15;
  const float* Wp = Wq + (i64)(h * 64) * 256;
  const float* Xp = fmap + (i64)b * 256 * NPIX + pxbase + i0;
  float acc[4][8];
  #pragma unroll
  for (int a = 0; a < 4; ++a)
    #pragma unroll
    for (int p = 0; p < 8; ++p) acc[a][p] = 0.f;

  for (int c0 = 0; c0 < 256; c0 += 16) {
    float4 wv  = *(const float4*)&Wp[(i64)(tid >> 2) * 256 + c0 + (tid & 3) * 4];
    float4 xv0 = *(const float4*)&Xp[(i64)(c0 + (tid >> 5)) * NPIX + (tid & 31) * 4];
    float4 xv1 = *(const float4*)&Xp[(i64)(c0 + 8 + (tid >> 5)) * NPIX + (tid & 31) * 4];
    __syncthreads();
    const int wr = (tid & 3) * 4, wc = tid >> 2;
    Ws[wr + 0][wc] = wv.x; Ws[wr + 1][wc] = wv.y; Ws[wr + 2][wc] = wv.z; Ws[wr + 3][wc] = wv.w;
    *(float4*)&Xs[tid >> 5][(tid & 31) * 4] = xv0;
    *(float4*)&Xs[8 + (tid >> 5)][(tid & 31) * 4] = xv1;
    __syncthreads();
    #pragma unroll
    for (int kc = 0; kc < 16; ++kc) {
      float4 w4 = *(const float4*)&Ws[kc][to * 4];
      float4 x0 = *(const float4*)&Xs[kc][tn * 4];
      float4 x1 = *(const float4*)&Xs[kc][64 + tn * 4];
      const float wa[4] = {w4.x, w4.y, w4.z, w4.w};
      const float xa[8] = {x0.x, x0.y, x0.z, x0.w, x1.x, x1.y, x1.z, x1.w};
      #pragma unroll
      for (int a = 0; a < 4; ++a)
        #pragma unroll
        for (int p = 0; p < 8; ++p)
          acc[a][p] = fmaf(wa[a], xa[p], acc[a][p]);
    }
  }
  // q tile -> LDS [ch][px]; stage ctx [d][e]
  #pragma unroll
  for (int a = 0; a < 4; ++a)
    #pragma unroll
    for (int p = 0; p < 8; ++p)
      qt[to * 4 + a][(p >> 2) * 64 + tn * 4 + (p & 3)] = acc[a][p];
  {
    const float* cp = ctx + (i64)(b * 8 + h) * 4096 + (i64)(tid >> 2) * 64 + (tid & 3) * 16;
    float4 c0v = *(const float4*)&cp[0];
    float4 c1v = *(const float4*)&cp[4];
    float4 c2v = *(const float4*)&cp[8];
    float4 c3v = *(const float4*)&cp[12];
    float* cd = &cs[tid >> 2][(tid & 3) * 16];
    *(float4*)&cd[0] = c0v; *(float4*)&cd[4] = c1v;
    *(float4*)&cd[8] = c2v; *(float4*)&cd[12] = c3v;
  }
  __syncthreads();
  // softmax over 64 features per pixel, * 0.125
  if (tid < 128) {
    const int px = tid;
    float m = -1e30f;
    #pragma unroll 8
    for (int c = 0; c < 64; ++c) m = fmaxf(m, qt[c][px]);
    float s = 0.f;
    #pragma unroll 8
    for (int c = 0; c < 64; ++c) { float e = expf(qt[c][px] - m); s += e; qt[c][px] = e; }
    float r = 0.125f / s;
    #pragma unroll 8
    for (int c = 0; c < 64; ++c) qt[c][px] *= r;
  }
  __syncthreads();
  // PV: out2[e, px] = sum_d qhat[d, px] * ctx[d, e]; e-group = to, px-group = tn
  float a3[4][8];
  #pragma unroll
  for (int e = 0; e < 4; ++e)
    #pragma unroll
    for (int p = 0; p < 8; ++p) a3[e][p] = 0.f;
  #pragma unroll 4
  for (int d = 0; d < 64; ++d) {
    float4 cv = *(const float4*)&cs[d][to * 4];
    float4 q0 = *(const float4*)&qt[d][tn * 8];
    float4 q1 = *(const float4*)&qt[d][tn * 8 + 4];
    const float ca[4] = {cv.x, cv.y, cv.z, cv.w};
    const float qa[8] = {q0.x, q0.y, q0.z, q0.w, q1.x, q1.y, q1.z, q1.w};
    #pragma unroll
    for (int e = 0; e < 4; ++e)
      #pragma unroll
      for (int p = 0; p < 8; ++p)
        a3[e][p] = fmaf(ca[e], qa[p], a3[e][p]);
  }
  // GELU (exact erf) + bf16 store
  #pragma unroll
  for (int e = 0; e < 4; ++e) {
    const int ch = h * 64 + to * 4 + e;
    __hip_bfloat16 tmp[8];
    #pragma unroll
    for (int p = 0; p < 8; ++p) {
      float v = a3[e][p];
      float g = 0.5f * v * (1.0f + erff(v * 0.70710678118654752f));
      tmp[p] = __float2bfloat16(g);
    }
    *(int4*)&out2[(i64)(b * 512 + ch) * NS + i0 + tn * 8] = *(const int4*)tmp;
  }
}

// ---------------- K7: out = Wout @ out2 + bout (out2 bf16 slice) -----------
__global__ __launch_bounds__(256) void wout_kernel(const float* __restrict__ Wout,
                                                   const __hip_bfloat16* __restrict__ out2,
                                                   const float* __restrict__ bout,
                                                   float* __restrict__ Y,
                                                   int pxbase, int NS) {
  __shared__ float Ws[16][68];
  __shared__ float Xs[16][132];
  const int b = blockIdx.z, o0 = blockIdx.y * 64;
  const int i0 = blockIdx.x * 128;                 // slice-local
  const int tid = threadIdx.x;
  const int to = tid >> 4, tn = tid & 15;
  float acc[4][8];
  #pragma unroll
  for (int a = 0; a < 4; ++a)
    #pragma unroll
    for (int p = 0; p < 8; ++p) acc[a][p] = 0.f;

  for (int c0 = 0; c0 < 512; c0 += 16) {
    float4 wv = *(const float4*)&Wout[(i64)(o0 + (tid >> 2)) * 512 + c0 + (tid & 3) * 4];
    int4 xr = *(const int4*)&out2[(i64)(b * 512 + c0 + (tid >> 4)) * NS + i0 + (tid & 15) * 8];
    __syncthreads();
    const int wr = (tid & 3) * 4, wc = tid >> 2;
    Ws[wr + 0][wc] = wv.x; Ws[wr + 1][wc] = wv.y; Ws[wr + 2][wc] = wv.z; Ws[wr + 3][wc] = wv.w;
    const __hip_bfloat16* hx = (const __hip_bfloat16*)&xr;
    #pragma unroll
    for (int j = 0; j < 8; ++j)
      Xs[tid >> 4][(tid & 15) * 8 + j] = __bfloat162float(hx[j]);
    __syncthreads();
    #pragma unroll
    for (int kc = 0; kc < 16; ++kc) {
      float4 w4 = *(const float4*)&Ws[kc][to * 4];
      float4 x0 = *(const float4*)&Xs[kc][tn * 4];
      float4 x1 = *(const float4*)&Xs[kc][64 + tn * 4];
      const float wa[4] = {w4.x, w4.y, w4.z, w4.w};
      const float xa[8] = {x0.x, x0.y, x0.z, x0.w, x1.x, x1.y, x1.z, x1.w};
      #pragma unroll
      for (int a = 0; a < 4; ++a)
        #pragma unroll
        for (int p = 0; p < 8; ++p)
          acc[a][p] = fmaf(wa[a], xa[p], acc[a][p]);
    }
  }
  #pragma unroll
  for (int a = 0; a < 4; ++a) {
    const int o = o0 + to * 4 + a;
    const float bv = bout[o];
    #pragma unroll
    for (int half = 0; half < 2; ++half) {
      float r[4];
      #pragma unroll
      for (int p = 0; p < 4; ++p) r[p] = acc[a][half * 4 + p] + bv;
      *(float4*)&Y[(i64)(b * 256 + o) * NPIX + pxbase + i0 + half * 64 + tn * 4] =
          make_float4(r[0], r[1], r[2], r[3]);
    }
  }
}

// ---------------------------------------------------------------------------
extern "C" void kernel_launch(void* const* d_in, const int* in_sizes, int n_in,
                              void* d_out, int out_size, void* d_ws, size_t ws_size,
                              hipStream_t stream) {
  const float* fmap = (const float*)d_in[0];
  const float* Wq   = (const float*)d_in[1];
  const float* Wdw  = (const float*)d_in[2];
  const float* Wpw  = (const float*)d_in[3];
  const float* Wout = (const float*)d_in[4];
  const float* bout = (const float*)d_in[5];
  float* out = (float*)d_out;
  float* dw  = out;                       // d_out (64 MB) doubles as dw scratch

  // ws layout (bytes):
  //   partM   [0,        1048576)
  //   partS   [1048576,  2097152)
  //   Mst     [2097152,  2129920)
  //   Ist     [2129920,  2162688)
  //   ctxpart [2162688,  10551296)      128 bh x 4 chunks x 64 x 64 fp32
  //   ctx     [10551296, 12648448)
  //   out2    [12648448, +64MB/S)       bf16, pixel-sliced
  char* ws = (char*)d_ws;
  float* partM = (float*)(ws + 0);
  float* partS = (float*)(ws + 1048576);
  float* Mst   = (float*)(ws + 2097152);
  float* Ist   = (float*)(ws + 2129920);
  float* part  = (float*)(ws + 2162688);
  float* ctx   = (float*)(ws + 10551296);
  __hip_bfloat16* out2 = (__hip_bfloat16*)(ws + 12648448);

  const size_t avail = ws_size > 12648448 ? ws_size - 12648448 : 0;
  int S;                                  // pixel slices for out2 double-pass
  if      (avail >= 67108864) S = 1;
  else if (avail >= 33554432) S = 2;
  else if (avail >= 16777216) S = 4;
  else if (avail >=  8388608) S = 8;
  else                        S = 16;
  const int NS = NPIX / S;

  dwconv_kernel<<<16 * 256 * 4096 / 256, 256, 0, stream>>>(fmap, Wdw, dw);
  kstats_kernel<<<dim3(32, 8, 16), 256, 0, stream>>>(Wpw, dw, partM, partS);
  kstats_reduce_kernel<<<32, 256, 0, stream>>>(partM, partS, Mst, Ist);
  context_kernel<<<dim3(4, 8, 16), 256, 0, stream>>>(Wpw, dw, Mst, Ist, part);
  ctx_reduce_kernel<<<2048, 256, 0, stream>>>(part, ctx);
  for (int s = 0; s < S; ++s) {
    qpv_kernel<<<dim3(NS / 128, 8, 16), 256, 0, stream>>>(Wq, fmap, ctx, out2, s * NS, NS);
    wout_kernel<<<dim3(NS / 128, 4, 16), 256, 0, stream>>>(Wout, out2, bout, out, s * NS, NS);
  }
}

// Round 3
// 869.927 us; speedup vs baseline: 1.8121x; 1.8121x over previous
//
#include <hip/hip_runtime.h>
#include <math.h>

// ---------------------------------------------------------------------------
// LinearAttention: B=16, DIM=256, H=W=64 (n=4096), HEADS=8, DH=64, INNER=512
// Round 3: split-bf16 MFMA (hi/lo error compensation ~= fp32 accuracy).
//   All GEMMs on matrix cores: C[ch][px] orientation, A=weights (row-major),
//   B=X staged fp32 -> bf16 hi/lo into [px][ch] LDS tiles (transpose during
//   convert). k-softmax/q-softmax computed WITHOUT max subtraction (values
//   bounded, exp safe in fp32; mathematically identical to reference).
// ---------------------------------------------------------------------------

static constexpr int NPIX = 4096;
typedef long long i64;
typedef __attribute__((ext_vector_type(8))) short s16x8;
typedef __attribute__((ext_vector_type(8))) __bf16 bf16x8;
typedef __attribute__((ext_vector_type(4))) float f32x4;

__device__ inline f32x4 MF(s16x8 a, s16x8 b, f32x4 c) {
  return __builtin_amdgcn_mfma_f32_16x16x32_bf16(
      __builtin_bit_cast(bf16x8, a), __builtin_bit_cast(bf16x8, b), c, 0, 0, 0);
}
__device__ inline unsigned short f2bf(float x) {
  unsigned u = __builtin_bit_cast(unsigned, x);
  u += 0x7fffu + ((u >> 16) & 1u);
  return (unsigned short)(u >> 16);
}
__device__ inline float bf2f(unsigned short h) {
  unsigned u = ((unsigned)h) << 16;
  return __builtin_bit_cast(float, u);
}
__device__ inline void split2(float x, unsigned short& hi, unsigned short& lo) {
  hi = f2bf(x);
  lo = f2bf(x - bf2f(hi));
}

#define LDX 40   // [i][c] stage row stride in shorts (32 c + 8 pad, 80B rows)
#define LDK 72   // [ch][i] GEMM2 buf row stride in shorts (64 i + 8 pad)

// ---------------- K1: depthwise 3x3, pad 1 (fp32, output -> d_out) ---------
__global__ __launch_bounds__(256) void dwconv_kernel(const float* __restrict__ fmap,
                                                     const float* __restrict__ Wdw,
                                                     float* __restrict__ dw) {
  i64 p = (i64)blockIdx.x * 256 + threadIdx.x;
  int y = (int)(p & 63);
  int x = (int)((p >> 6) & 63);
  int c = (int)((p >> 12) & 255);
  const float* img = fmap + (p >> 12) * (i64)NPIX;
  const float* w = Wdw + c * 9;
  float s = 0.f;
  #pragma unroll
  for (int dx = -1; dx <= 1; ++dx) {
    int xx = x + dx;
    if ((unsigned)xx < 64u) {
      #pragma unroll
      for (int dy = -1; dy <= 1; ++dy) {
        int yy = y + dy;
        if ((unsigned)yy < 64u)
          s = fmaf(w[(dx + 1) * 3 + (dy + 1)], img[xx * 64 + yy], s);
      }
    }
  }
  dw[p] = s;
}

// ---------------- K2: split weights into bf16 hi/lo ------------------------
// layout in whi/wlo (shorts): Wq [0,131072) | Wpw [131072,393216) | Wout [393216,524288)
__global__ __launch_bounds__(256) void wprep_kernel(const float* __restrict__ Wq,
                                                    const float* __restrict__ Wpw,
                                                    const float* __restrict__ Wout,
                                                    short* __restrict__ whi,
                                                    short* __restrict__ wlo) {
  int i = blockIdx.x * 256 + threadIdx.x;
  float v;
  if (i < 131072) v = Wq[i];
  else if (i < 393216) v = Wpw[i - 131072];
  else v = Wout[i - 393216];
  unsigned short h, l;
  split2(v, h, l);
  whi[i] = (short)h;
  wlo[i] = (short)l;
}

// ---------------- K3: fused k/v GEMM + exp + ctx partial -------------------
// grid (4 chunks, 8 h, 16 b). Block: M=128 (64 kch + 64 vch) x N=128 px,
// K=256. waves: (wch = k/v half) x (wih = i half); wave tile 64ch x 64i.
// GEMM2 (ctx += khat^T . v) per 64-i phase via LDS round-trip.
__global__ __launch_bounds__(256) void ctx_kernel(const short* __restrict__ whi,
                                                  const short* __restrict__ wlo,
                                                  const float* __restrict__ dw,
                                                  float* __restrict__ ctx_part,
                                                  float* __restrict__ s_part) {
  __shared__ short XsH[128 * LDX], XsL[128 * LDX];
  __shared__ short khH[64 * LDK], khL[64 * LDK];
  __shared__ short vvH[64 * LDK], vvL[64 * LDK];
  __shared__ float sred[2][64];
  const int chunk = blockIdx.x, h = blockIdx.y, b = blockIdx.z;
  const int tid = threadIdx.x;
  const int lane = tid & 63, w = tid >> 6;
  const int fr = lane & 15, fg = lane >> 4;
  const int wch = w & 1;    // 0 = k-half, 1 = v-half
  const int wih = w >> 1;   // i-half
  const int dq = wch, eq = wih;  // GEMM2 ctx quadrant

  const int wrow0 = wch ? (512 + h * 64) : (h * 64);
  const short* WH = whi + 131072 + (i64)wrow0 * 256;
  const short* WL = wlo + 131072 + (i64)wrow0 * 256;
  const float* Xg = dw + (i64)b * 256 * NPIX + chunk * 1024;

  f32x4 acc2[2][2];
  #pragma unroll
  for (int m = 0; m < 2; ++m)
    #pragma unroll
    for (int n = 0; n < 2; ++n) acc2[m][n] = (f32x4)0.f;
  float srun[16];
  #pragma unroll
  for (int t = 0; t < 16; ++t) srun[t] = 0.f;

  for (int it = 0; it < 8; ++it) {
    f32x4 acc1[4][4];
    #pragma unroll
    for (int m = 0; m < 4; ++m)
      #pragma unroll
      for (int n = 0; n < 4; ++n) acc1[m][n] = (f32x4)0.f;

    for (int ks = 0; ks < 8; ++ks) {
      const int c0 = ks * 32;
      __syncthreads();
      #pragma unroll
      for (int uu = 0; uu < 2; ++uu) {
        const int u = tid + uu * 256;
        const int cp = u >> 5, ig = u & 31;
        const int c = c0 + cp * 2, ii = ig * 4;
        f32x4 v0 = *(const f32x4*)&Xg[(i64)c * NPIX + it * 128 + ii];
        f32x4 v1 = *(const f32x4*)&Xg[(i64)(c + 1) * NPIX + it * 128 + ii];
        #pragma unroll
        for (int j = 0; j < 4; ++j) {
          unsigned short h0, l0, h1, l1;
          split2(v0[j], h0, l0);
          split2(v1[j], h1, l1);
          *(unsigned*)&XsH[(ii + j) * LDX + cp * 2] = (unsigned)h0 | ((unsigned)h1 << 16);
          *(unsigned*)&XsL[(ii + j) * LDX + cp * 2] = (unsigned)l0 | ((unsigned)l1 << 16);
        }
      }
      __syncthreads();
      s16x8 aH[4], aL[4], bH[4], bL[4];
      #pragma unroll
      for (int m = 0; m < 4; ++m) {
        const int row = m * 16 + fr;
        aH[m] = *(const s16x8*)&WH[(i64)row * 256 + c0 + fg * 8];
        aL[m] = *(const s16x8*)&WL[(i64)row * 256 + c0 + fg * 8];
      }
      #pragma unroll
      for (int n = 0; n < 4; ++n) {
        const int ir = wih * 64 + n * 16 + fr;
        bH[n] = *(const s16x8*)&XsH[ir * LDX + fg * 8];
        bL[n] = *(const s16x8*)&XsL[ir * LDX + fg * 8];
      }
      #pragma unroll
      for (int m = 0; m < 4; ++m)
        #pragma unroll
        for (int n = 0; n < 4; ++n) {
          acc1[m][n] = MF(aH[m], bH[n], acc1[m][n]);
          acc1[m][n] = MF(aH[m], bL[n], acc1[m][n]);
          acc1[m][n] = MF(aL[m], bH[n], acc1[m][n]);
        }
    }
    // k-half: khat = exp(k) (no max-sub; values bounded), accumulate sum
    if (wch == 0) {
      #pragma unroll
      for (int m = 0; m < 4; ++m)
        #pragma unroll
        for (int n = 0; n < 4; ++n)
          #pragma unroll
          for (int r = 0; r < 4; ++r) {
            float e = expf(acc1[m][n][r]);
            acc1[m][n][r] = e;
            srun[m * 4 + r] += e;
          }
    }
    // two GEMM2 phases (64 i each)
    #pragma unroll
    for (int ph = 0; ph < 2; ++ph) {
      __syncthreads();
      if (wih == ph) {
        short* dH = wch ? vvH : khH;
        short* dL = wch ? vvL : khL;
        #pragma unroll
        for (int m = 0; m < 4; ++m)
          #pragma unroll
          for (int n = 0; n < 4; ++n) {
            const int ch = m * 16 + fg * 4;
            const int il = n * 16 + fr;
            #pragma unroll
            for (int r = 0; r < 4; ++r) {
              unsigned short hh, ll;
              split2(acc1[m][n][r], hh, ll);
              dH[(ch + r) * LDK + il] = (short)hh;
              dL[(ch + r) * LDK + il] = (short)ll;
            }
          }
      }
      __syncthreads();
      #pragma unroll
      for (int k2 = 0; k2 < 2; ++k2) {
        s16x8 a2H[2], a2L[2], b2H[2], b2L[2];
        #pragma unroll
        for (int m2 = 0; m2 < 2; ++m2) {
          const int d = dq * 32 + m2 * 16 + fr;
          a2H[m2] = *(const s16x8*)&khH[d * LDK + k2 * 32 + fg * 8];
          a2L[m2] = *(const s16x8*)&khL[d * LDK + k2 * 32 + fg * 8];
        }
        #pragma unroll
        for (int n2 = 0; n2 < 2; ++n2) {
          const int e = eq * 32 + n2 * 16 + fr;
          b2H[n2] = *(const s16x8*)&vvH[e * LDK + k2 * 32 + fg * 8];
          b2L[n2] = *(const s16x8*)&vvL[e * LDK + k2 * 32 + fg * 8];
        }
        #pragma unroll
        for (int m2 = 0; m2 < 2; ++m2)
          #pragma unroll
          for (int n2 = 0; n2 < 2; ++n2) {
            acc2[m2][n2] = MF(a2H[m2], b2H[n2], acc2[m2][n2]);
            acc2[m2][n2] = MF(a2H[m2], b2L[n2], acc2[m2][n2]);
            acc2[m2][n2] = MF(a2L[m2], b2H[n2], acc2[m2][n2]);
          }
      }
    }
  }
  __syncthreads();
  // write ctx partial [d][e]
  float* cp = ctx_part + (i64)((b * 8 + h) * 4 + chunk) * 4096;
  #pragma unroll
  for (int m2 = 0; m2 < 2; ++m2)
    #pragma unroll
    for (int n2 = 0; n2 < 2; ++n2)
      #pragma unroll
      for (int r = 0; r < 4; ++r) {
        const int d = dq * 32 + m2 * 16 + fg * 4 + r;
        const int e = eq * 32 + n2 * 16 + fr;
        cp[d * 64 + e] = acc2[m2][n2][r];
      }
  // reduce + write sumexp partial per k channel
  if (wch == 0) {
    #pragma unroll
    for (int t = 0; t < 16; ++t) {
      float s = srun[t];
      s += __shfl_xor(s, 1); s += __shfl_xor(s, 2);
      s += __shfl_xor(s, 4); s += __shfl_xor(s, 8);
      if (fr == 0) sred[wih][(t >> 2) * 16 + fg * 4 + (t & 3)] = s;
    }
  }
  __syncthreads();
  if (tid < 64)
    s_part[(i64)((b * 8 + h) * 4 + chunk) * 64 + tid] = sred[0][tid] + sred[1][tid];
}

// ---------------- K4: merge chunk partials -> ctx[e][d] bf16 hi/lo ---------
__global__ __launch_bounds__(256) void merge_kernel(const float* __restrict__ part,
                                                    const float* __restrict__ s_part,
                                                    short* __restrict__ ctxH,
                                                    short* __restrict__ ctxL) {
  const int bh = blockIdx.x, t = threadIdx.x;
  const int e = t & 63, dband = t >> 6;
  const float* p = part + (i64)bh * 4 * 4096;
  const float* sp = s_part + (i64)bh * 4 * 64;
  #pragma unroll 4
  for (int dd = 0; dd < 16; ++dd) {
    const int d = dband * 16 + dd;
    float s = sp[d] + sp[64 + d] + sp[128 + d] + sp[192 + d];
    float c = p[d * 64 + e] + p[4096 + d * 64 + e] + p[8192 + d * 64 + e] + p[12288 + d * 64 + e];
    float v = c / s;
    unsigned short hh, ll;
    split2(v, hh, ll);
    ctxH[(i64)bh * 4096 + e * 64 + d] = (short)hh;
    ctxL[(i64)bh * 4096 + e * 64 + d] = (short)ll;
  }
}

// ---------------- K5: fused q GEMM + softmax + PV + GELU -> out2 (u32) -----
// grid (NS/128, 8 h, 16 b). M=64 d x N=128 px, K=256.
__global__ __launch_bounds__(256) void qpv_kernel(const short* __restrict__ whi,
                                                  const short* __restrict__ wlo,
                                                  const float* __restrict__ fmap,
                                                  const short* __restrict__ ctxH,
                                                  const short* __restrict__ ctxL,
                                                  unsigned* __restrict__ out2,
                                                  int pxbase, int NS) {
  __shared__ short XsH[128 * LDX], XsL[128 * LDX];
  __shared__ short qhH[128 * LDK], qhL[128 * LDK];
  __shared__ float sden[2][128];
  const int h = blockIdx.y, b = blockIdx.z;
  const int i0 = blockIdx.x * 128;
  const int tid = threadIdx.x;
  const int lane = tid & 63, w = tid >> 6;
  const int fr = lane & 15, fg = lane >> 4;
  const int dh = w & 1, ih = w >> 1;

  const short* WH = whi + (i64)(h * 64 + dh * 32) * 256;
  const short* WL = wlo + (i64)(h * 64 + dh * 32) * 256;
  const float* Xg = fmap + (i64)b * 256 * NPIX + pxbase + i0;

  f32x4 acc[2][4];
  #pragma unroll
  for (int m = 0; m < 2; ++m)
    #pragma unroll
    for (int n = 0; n < 4; ++n) acc[m][n] = (f32x4)0.f;

  for (int ks = 0; ks < 8; ++ks) {
    const int c0 = ks * 32;
    __syncthreads();
    #pragma unroll
    for (int uu = 0; uu < 2; ++uu) {
      const int u = tid + uu * 256;
      const int cp = u >> 5, ig = u & 31;
      const int c = c0 + cp * 2, ii = ig * 4;
      f32x4 v0 = *(const f32x4*)&Xg[(i64)c * NPIX + ii];
      f32x4 v1 = *(const f32x4*)&Xg[(i64)(c + 1) * NPIX + ii];
      #pragma unroll
      for (int j = 0; j < 4; ++j) {
        unsigned short h0, l0, h1, l1;
        split2(v0[j], h0, l0);
        split2(v1[j], h1, l1);
        *(unsigned*)&XsH[(ii + j) * LDX + cp * 2] = (unsigned)h0 | ((unsigned)h1 << 16);
        *(unsigned*)&XsL[(ii + j) * LDX + cp * 2] = (unsigned)l0 | ((unsigned)l1 << 16);
      }
    }
    __syncthreads();
    s16x8 aH[2], aL[2], bH[4], bL[4];
    #pragma unroll
    for (int m = 0; m < 2; ++m) {
      const int row = m * 16 + fr;
      aH[m] = *(const s16x8*)&WH[(i64)row * 256 + c0 + fg * 8];
      aL[m] = *(const s16x8*)&WL[(i64)row * 256 + c0 + fg * 8];
    }
    #pragma unroll
    for (int n = 0; n < 4; ++n) {
      const int ir = ih * 64 + n * 16 + fr;
      bH[n] = *(const s16x8*)&XsH[ir * LDX + fg * 8];
      bL[n] = *(const s16x8*)&XsL[ir * LDX + fg * 8];
    }
    #pragma unroll
    for (int m = 0; m < 2; ++m)
      #pragma unroll
      for (int n = 0; n < 4; ++n) {
        acc[m][n] = MF(aH[m], bH[n], acc[m][n]);
        acc[m][n] = MF(aH[m], bL[n], acc[m][n]);
        acc[m][n] = MF(aL[m], bH[n], acc[m][n]);
      }
  }
  // exp (no max-sub) + per-pixel denominator across both d-half waves
  float colsum[4];
  #pragma unroll
  for (int n = 0; n < 4; ++n) {
    float s = 0.f;
    #pragma unroll
    for (int m = 0; m < 2; ++m)
      #pragma unroll
      for (int r = 0; r < 4; ++r) {
        float e = expf(acc[m][n][r]);
        acc[m][n][r] = e;
        s += e;
      }
    s += __shfl_xor(s, 16);
    s += __shfl_xor(s, 32);
    colsum[n] = s;
  }
  if (fg == 0) {
    #pragma unroll
    for (int n = 0; n < 4; ++n) sden[dh][ih * 64 + n * 16 + fr] = colsum[n];
  }
  __syncthreads();
  if (tid < 128) sden[0][tid] += sden[1][tid];
  __syncthreads();
  // qhat = exp * (0.125/sum) -> LDS [i][d] hi/lo (b64 packed writes)
  #pragma unroll
  for (int n = 0; n < 4; ++n) {
    const int il = ih * 64 + n * 16 + fr;
    const float r = 0.125f / sden[0][il];
    #pragma unroll
    for (int m = 0; m < 2; ++m) {
      const int d0 = dh * 32 + m * 16 + fg * 4;
      unsigned short hh[4], ll[4];
      #pragma unroll
      for (int rr = 0; rr < 4; ++rr) split2(acc[m][n][rr] * r, hh[rr], ll[rr]);
      uint2 ph, pl;
      ph.x = (unsigned)hh[0] | ((unsigned)hh[1] << 16);
      ph.y = (unsigned)hh[2] | ((unsigned)hh[3] << 16);
      pl.x = (unsigned)ll[0] | ((unsigned)ll[1] << 16);
      pl.y = (unsigned)ll[2] | ((unsigned)ll[3] << 16);
      *(uint2*)&qhH[il * LDK + d0] = ph;
      *(uint2*)&qhL[il * LDK + d0] = pl;
    }
  }
  __syncthreads();
  // PV: out2[e][i] = sum_d qhat[d][i]*ctx[e][d]  (A=ctx [e][d], B=qhat [i][d])
  f32x4 acc3[2][4];
  #pragma unroll
  for (int m = 0; m < 2; ++m)
    #pragma unroll
    for (int n = 0; n < 4; ++n) acc3[m][n] = (f32x4)0.f;
  const i64 cbase = (i64)(b * 8 + h) * 4096;
  #pragma unroll
  for (int k2 = 0; k2 < 2; ++k2) {
    s16x8 a2H[2], a2L[2], b2H[4], b2L[4];
    #pragma unroll
    for (int m2 = 0; m2 < 2; ++m2) {
      const int e = dh * 32 + m2 * 16 + fr;
      a2H[m2] = *(const s16x8*)&ctxH[cbase + e * 64 + k2 * 32 + fg * 8];
      a2L[m2] = *(const s16x8*)&ctxL[cbase + e * 64 + k2 * 32 + fg * 8];
    }
    #pragma unroll
    for (int n2 = 0; n2 < 4; ++n2) {
      const int il = ih * 64 + n2 * 16 + fr;
      b2H[n2] = *(const s16x8*)&qhH[il * LDK + k2 * 32 + fg * 8];
      b2L[n2] = *(const s16x8*)&qhL[il * LDK + k2 * 32 + fg * 8];
    }
    #pragma unroll
    for (int m2 = 0; m2 < 2; ++m2)
      #pragma unroll
      for (int n2 = 0; n2 < 4; ++n2) {
        acc3[m2][n2] = MF(a2H[m2], b2H[n2], acc3[m2][n2]);
        acc3[m2][n2] = MF(a2H[m2], b2L[n2], acc3[m2][n2]);
        acc3[m2][n2] = MF(a2L[m2], b2H[n2], acc3[m2][n2]);
      }
  }
  // GELU (exact erf) + packed hi/lo store
  #pragma unroll
  for (int m2 = 0; m2 < 2; ++m2)
    #pragma unroll
    for (int n2 = 0; n2 < 4; ++n2) {
      const int il = ih * 64 + n2 * 16 + fr;
      #pragma unroll
      for (int rr = 0; rr < 4; ++rr) {
        const int e = dh * 32 + m2 * 16 + fg * 4 + rr;
        float v = acc3[m2][n2][rr];
        float g = 0.5f * v * (1.0f + erff(v * 0.70710678118654752f));
        unsigned short hh, ll;
        split2(g, hh, ll);
        out2[(i64)(b * 512 + h * 64 + e) * NS + i0 + il] = (unsigned)hh | ((unsigned)ll << 16);
      }
    }
}

// ---------------- K6: out = Wout @ out2 + bout ----------------------------
// grid (NS/128, 4 og, 16 b). M=64 o x N=128 px, K=512.
__global__ __launch_bounds__(256) void wout_kernel(const short* __restrict__ whi,
                                                   const short* __restrict__ wlo,
                                                   const unsigned* __restrict__ out2,
                                                   const float* __restrict__ bout,
                                                   float* __restrict__ Y,
                                                   int pxbase, int NS) {
  __shared__ short XsH[128 * LDX], XsL[128 * LDX];
  const int og = blockIdx.y, b = blockIdx.z;
  const int i0 = blockIdx.x * 128;
  const int tid = threadIdx.x;
  const int lane = tid & 63, w = tid >> 6;
  const int fr = lane & 15, fg = lane >> 4;
  const int oh = w & 1, ih = w >> 1;

  const short* WH = whi + 393216 + (i64)(og * 64 + oh * 32) * 512;
  const short* WL = wlo + 393216 + (i64)(og * 64 + oh * 32) * 512;

  f32x4 acc[2][4];
  #pragma unroll
  for (int m = 0; m < 2; ++m)
    #pragma unroll
    for (int n = 0; n < 4; ++n) acc[m][n] = (f32x4)0.f;

  for (int ks = 0; ks < 16; ++ks) {
    const int c0 = ks * 32;
    __syncthreads();
    #pragma unroll
    for (int uu = 0; uu < 2; ++uu) {
      const int u = tid + uu * 256;
      const int cp = u >> 5, ig = u & 31;
      const int c = c0 + cp * 2, ii = ig * 4;
      uint4 r0 = *(const uint4*)&out2[(i64)(b * 512 + c) * NS + i0 + ii];
      uint4 r1 = *(const uint4*)&out2[(i64)(b * 512 + c + 1) * NS + i0 + ii];
      const unsigned* a0 = (const unsigned*)&r0;
      const unsigned* a1 = (const unsigned*)&r1;
      #pragma unroll
      for (int j = 0; j < 4; ++j) {
        *(unsigned*)&XsH[(ii + j) * LDX + cp * 2] = (a0[j] & 0xffffu) | (a1[j] << 16);
        *(unsigned*)&XsL[(ii + j) * LDX + cp * 2] = (a0[j] >> 16) | (a1[j] & 0xffff0000u);
      }
    }
    __syncthreads();
    s16x8 aH[2], aL[2], bH[4], bL[4];
    #pragma unroll
    for (int m = 0; m < 2; ++m) {
      const int row = m * 16 + fr;
      aH[m] = *(const s16x8*)&WH[(i64)row * 512 + c0 + fg * 8];
      aL[m] = *(const s16x8*)&WL[(i64)row * 512 + c0 + fg * 8];
    }
    #pragma unroll
    for (int n = 0; n < 4; ++n) {
      const int ir = ih * 64 + n * 16 + fr;
      bH[n] = *(const s16x8*)&XsH[ir * LDX + fg * 8];
      bL[n] = *(const s16x8*)&XsL[ir * LDX + fg * 8];
    }
    #pragma unroll
    for (int m = 0; m < 2; ++m)
      #pragma unroll
      for (int n = 0; n < 4; ++n) {
        acc[m][n] = MF(aH[m], bH[n], acc[m][n]);
        acc[m][n] = MF(aH[m], bL[n], acc[m][n]);
        acc[m][n] = MF(aL[m], bH[n], acc[m][n]);
      }
  }
  #pragma unroll
  for (int m = 0; m < 2; ++m)
    #pragma unroll
    for (int rr = 0; rr < 4; ++rr) {
      const int o = og * 64 + oh * 32 + m * 16 + fg * 4 + rr;
      const float bv = bout[o];
      #pragma unroll
      for (int n = 0; n < 4; ++n) {
        const int il = ih * 64 + n * 16 + fr;
        Y[(i64)(b * 256 + o) * NPIX + pxbase + i0 + il] = acc[m][n][rr] + bv;
      }
    }
}

// ---------------------------------------------------------------------------
extern "C" void kernel_launch(void* const* d_in, const int* in_sizes, int n_in,
                              void* d_out, int out_size, void* d_ws, size_t ws_size,
                              hipStream_t stream) {
  const float* fmap = (const float*)d_in[0];
  const float* Wq   = (const float*)d_in[1];
  const float* Wdw  = (const float*)d_in[2];
  const float* Wpw  = (const float*)d_in[3];
  const float* Wout = (const float*)d_in[4];
  const float* bout = (const float*)d_in[5];
  float* out = (float*)d_out;
  float* dw  = out;   // d_out doubles as dw scratch (dead before wout writes)

  // ws layout (bytes):
  //   whi      [0,        1048576)
  //   wlo      [1048576,  2097152)
  //   s_part   [2097152,  2228224)   128bh x 4 x 64 fp32
  //   ctx_part [2228224,  10616832)  128bh x 4 x 64 x 64 fp32
  //   ctxH     [10616832, 11665408)  128bh x 64e x 64d bf16
  //   ctxL     [11665408, 12713984)
  //   out2     [12713984, +128MB/S)  u32(hi|lo) [b][512][NS], pixel-sliced
  char* ws = (char*)d_ws;
  short* whi      = (short*)(ws);
  short* wlo      = (short*)(ws + 1048576);
  float* s_part   = (float*)(ws + 2097152);
  float* ctx_part = (float*)(ws + 2228224);
  short* ctxH     = (short*)(ws + 10616832);
  short* ctxL     = (short*)(ws + 11665408);
  unsigned* out2  = (unsigned*)(ws + 12713984);

  const size_t avail = ws_size > 12713984 ? ws_size - 12713984 : 0;
  int S;
  if      (avail >= 134217728) S = 1;
  else if (avail >=  67108864) S = 2;
  else if (avail >=  33554432) S = 4;
  else if (avail >=  16777216) S = 8;
  else if (avail >=   8388608) S = 16;
  else                         S = 32;
  const int NS = NPIX / S;

  dwconv_kernel<<<16 * 256 * 4096 / 256, 256, 0, stream>>>(fmap, Wdw, dw);
  wprep_kernel<<<2048, 256, 0, stream>>>(Wq, Wpw, Wout, whi, wlo);
  ctx_kernel<<<dim3(4, 8, 16), 256, 0, stream>>>(whi, wlo, dw, ctx_part, s_part);
  merge_kernel<<<128, 256, 0, stream>>>(ctx_part, s_part, ctxH, ctxL);
  for (int s = 0; s < S; ++s) {
    qpv_kernel<<<dim3(NS / 128, 8, 16), 256, 0, stream>>>(whi, wlo, fmap, ctxH, ctxL,
                                                          out2, s * NS, NS);
    wout_kernel<<<dim3(NS / 128, 4, 16), 256, 0, stream>>>(whi, wlo, out2, bout, out,
                                                           s * NS, NS);
  }
}

// Round 5
// 426.010 us; speedup vs baseline: 3.7005x; 2.0420x over previous
//
#include <hip/hip_runtime.h>
#include <math.h>

// ---------------------------------------------------------------------------
// LinearAttention: B=16, DIM=256, H=W=64 (n=4096), HEADS=8, DH=64, INNER=512
// Round 5: single-fp16 MFMA (fix round-4 bug: staging covered only half the
// X tile -> uninitialized LDS -> NaN). Each thread now stages TWO s16x8
// chunks (rows tid>>2 and 64+(tid>>2)), loads prefetched before the barrier.
// ---------------------------------------------------------------------------

static constexpr int NPIX = 4096;
typedef long long i64;
typedef __attribute__((ext_vector_type(8))) short s16x8;
typedef __attribute__((ext_vector_type(8))) _Float16 f16x8;
typedef __attribute__((ext_vector_type(4))) float f32x4;

__device__ inline f32x4 MF(s16x8 a, s16x8 b, f32x4 c) {
  return __builtin_amdgcn_mfma_f32_16x16x32_f16(
      __builtin_bit_cast(f16x8, a), __builtin_bit_cast(f16x8, b), c, 0, 0, 0);
}
__device__ inline short f2h(float x) {
  return __builtin_bit_cast(short, (_Float16)x);
}

#define LDX 40    // Xs row stride in shorts (32 c + 8 pad, 80B = 5*16B)
#define LDK 136   // kh/vv row stride in shorts (128 px + 8 pad, 272B = 17*16B)
#define LDQ 72    // qh row stride in shorts (64 + 8 pad, 144B = 9*16B)

// ---------------- K1: depthwise 3x3, pad 1 (fp32 -> d_out) -----------------
__global__ __launch_bounds__(256) void dwconv_kernel(const float* __restrict__ fmap,
                                                     const float* __restrict__ Wdw,
                                                     float* __restrict__ dw) {
  i64 p = (i64)blockIdx.x * 256 + threadIdx.x;
  int y = (int)(p & 63);
  int x = (int)((p >> 6) & 63);
  int c = (int)((p >> 12) & 255);
  const float* img = fmap + (p >> 12) * (i64)NPIX;
  const float* w = Wdw + c * 9;
  float s = 0.f;
  #pragma unroll
  for (int dx = -1; dx <= 1; ++dx) {
    int xx = x + dx;
    if ((unsigned)xx < 64u) {
      #pragma unroll
      for (int dy = -1; dy <= 1; ++dy) {
        int yy = y + dy;
        if ((unsigned)yy < 64u)
          s = fmaf(w[(dx + 1) * 3 + (dy + 1)], img[xx * 64 + yy], s);
      }
    }
  }
  dw[p] = s;
}

// ---------------- K2: weights -> fp16 --------------------------------------
// wh layout (shorts): Wq [0,131072) | Wpw [131072,393216) | Wout [393216,524288)
__global__ __launch_bounds__(256) void wprep_kernel(const float* __restrict__ Wq,
                                                    const float* __restrict__ Wpw,
                                                    const float* __restrict__ Wout,
                                                    short* __restrict__ wh) {
  int i = blockIdx.x * 256 + threadIdx.x;
  float v;
  if (i < 131072) v = Wq[i];
  else if (i < 393216) v = Wpw[i - 131072];
  else v = Wout[i - 393216];
  wh[i] = f2h(v);
}

// ---------------- K3: transpose+convert fp32 [c][px] -> fp16 [px][c] -------
// tile: 64 c x 256 px. grid (npx/256, 4, 16).
__global__ __launch_bounds__(256) void tcvt_kernel(const float* __restrict__ src,
                                                   short* __restrict__ dst,
                                                   int src_px0, int nsl) {
  __shared__ short T[64 * 260];
  const int pxt = blockIdx.x * 256, ct = blockIdx.y * 64, b = blockIdx.z;
  const int t = threadIdx.x;
  const int pxq = t & 63, cl = t >> 6;
  const float* sp = src + (i64)(b * 256 + ct) * NPIX + src_px0 + pxt;
  #pragma unroll
  for (int cc = 0; cc < 16; ++cc) {
    const int c = cl + cc * 4;
    f32x4 v = *(const f32x4*)&sp[(i64)c * NPIX + pxq * 4];
    unsigned lo = (unsigned short)f2h(v[0]) | ((unsigned)(unsigned short)f2h(v[1]) << 16);
    unsigned hi = (unsigned short)f2h(v[2]) | ((unsigned)(unsigned short)f2h(v[3]) << 16);
    *(uint2*)&T[c * 260 + pxq * 4] = make_uint2(lo, hi);
  }
  __syncthreads();
  short arr[64];
  #pragma unroll
  for (int c = 0; c < 64; ++c) arr[c] = T[c * 260 + t];
  short* dp = dst + ((i64)b * nsl + pxt + t) * 256 + ct;
  #pragma unroll
  for (int j = 0; j < 8; ++j)
    *(uint4*)&dp[j * 8] = *(const uint4*)&arr[j * 8];
}

// ---------------- K4: fused k/v GEMM + exp + ctx partial -------------------
// grid (8 chunks of 512 px, 8 h, 16 b). Block M=128 (64 k + 64 v) x N=128 px
// per it (4 its), K=256. Waves: wch (k/v half) x wih (px half).
__global__ __launch_bounds__(256) void ctx_kernel(const short* __restrict__ wh,
                                                  const short* __restrict__ dwT,
                                                  float* __restrict__ ctx_part,
                                                  float* __restrict__ s_part) {
  __shared__ short Xs[128 * LDX];
  __shared__ short kh[64 * LDK];
  __shared__ short vv[64 * LDK];
  __shared__ float sred[2][64];
  const int chunk = blockIdx.x, h = blockIdx.y, b = blockIdx.z;
  const int tid = threadIdx.x, lane = tid & 63, w = tid >> 6;
  const int fr = lane & 15, fg = lane >> 4;
  const int wch = w & 1, wih = w >> 1;
  const int wrow0 = wch ? (512 + h * 64) : (h * 64);
  const short* W = wh + 131072 + (i64)wrow0 * 256;
  const short* Xg = dwT + ((i64)b * NPIX + chunk * 512) * 256;

  f32x4 acc2[2][2];
  #pragma unroll
  for (int m = 0; m < 2; ++m)
    #pragma unroll
    for (int n = 0; n < 2; ++n) acc2[m][n] = (f32x4)0.f;
  float srun[16];
  #pragma unroll
  for (int t = 0; t < 16; ++t) srun[t] = 0.f;

  // staging coords: each thread handles rows r0 and r0+64, col-quad scq
  const int r0 = tid >> 2, scq = tid & 3;
  const int sg0 = (scq ^ ((r0 >> 4) & 3)) * 8;
  const int sg1 = (scq ^ (((r0 + 64) >> 4) & 3)) * 8;

  for (int it = 0; it < 4; ++it) {
    f32x4 acc1[4][4];
    #pragma unroll
    for (int m = 0; m < 4; ++m)
      #pragma unroll
      for (int n = 0; n < 4; ++n) acc1[m][n] = (f32x4)0.f;

    for (int ks = 0; ks < 8; ++ks) {
      const int c0 = ks * 32;
      s16x8 sv0 = *(const s16x8*)&Xg[(i64)(it * 128 + r0) * 256 + c0 + scq * 8];
      s16x8 sv1 = *(const s16x8*)&Xg[(i64)(it * 128 + r0 + 64) * 256 + c0 + scq * 8];
      __syncthreads();
      *(s16x8*)&Xs[r0 * LDX + sg0] = sv0;
      *(s16x8*)&Xs[(r0 + 64) * LDX + sg1] = sv1;
      __syncthreads();
      s16x8 a[4], bfr[4];
      #pragma unroll
      for (int m = 0; m < 4; ++m)
        a[m] = *(const s16x8*)&W[(i64)(m * 16 + fr) * 256 + c0 + fg * 8];
      #pragma unroll
      for (int n = 0; n < 4; ++n)
        bfr[n] = *(const s16x8*)&Xs[(wih * 64 + n * 16 + fr) * LDX + ((fg ^ (n & 3)) * 8)];
      #pragma unroll
      for (int m = 0; m < 4; ++m)
        #pragma unroll
        for (int n = 0; n < 4; ++n)
          acc1[m][n] = MF(a[m], bfr[n], acc1[m][n]);
    }
    // k-half: exp (no max-sub; values bounded), accumulate channel sums
    if (wch == 0) {
      #pragma unroll
      for (int m = 0; m < 4; ++m)
        #pragma unroll
        for (int n = 0; n < 4; ++n)
          #pragma unroll
          for (int r = 0; r < 4; ++r) {
            float e = __expf(acc1[m][n][r]);
            acc1[m][n][r] = e;
            srun[m * 4 + r] += e;
          }
    }
    // write khat / v tiles (fp16, px-group XOR swizzle), one barrier
    {
      short* dst = wch ? vv : kh;
      #pragma unroll
      for (int m = 0; m < 4; ++m)
        #pragma unroll
        for (int n = 0; n < 4; ++n)
          #pragma unroll
          for (int r = 0; r < 4; ++r) {
            const int ch = m * 16 + fg * 4 + r;
            const int px = wih * 64 + n * 16 + fr;
            const int col = (((px >> 3) ^ (ch & 3)) * 8) + (px & 7);
            dst[ch * LDK + col] = f2h(acc1[m][n][r]);
          }
    }
    __syncthreads();
    // GEMM2: ctx[d][e] += sum_px kh[d][px] * vv[e][px]; quadrant (wch, wih)
    #pragma unroll
    for (int k2 = 0; k2 < 4; ++k2) {
      const int colg = ((k2 * 4 + fg) ^ (fr & 3)) * 8;
      s16x8 a2[2], b2[2];
      #pragma unroll
      for (int m2 = 0; m2 < 2; ++m2)
        a2[m2] = *(const s16x8*)&kh[(wch * 32 + m2 * 16 + fr) * LDK + colg];
      #pragma unroll
      for (int n2 = 0; n2 < 2; ++n2)
        b2[n2] = *(const s16x8*)&vv[(wih * 32 + n2 * 16 + fr) * LDK + colg];
      #pragma unroll
      for (int m2 = 0; m2 < 2; ++m2)
        #pragma unroll
        for (int n2 = 0; n2 < 2; ++n2)
          acc2[m2][n2] = MF(a2[m2], b2[n2], acc2[m2][n2]);
    }
    __syncthreads();   // kh/vv consumed before next it overwrites
  }
  // write ctx partial [d][e]
  float* cp = ctx_part + (i64)((b * 8 + h) * 8 + chunk) * 4096;
  #pragma unroll
  for (int m2 = 0; m2 < 2; ++m2)
    #pragma unroll
    for (int n2 = 0; n2 < 2; ++n2)
      #pragma unroll
      for (int r = 0; r < 4; ++r) {
        const int d = wch * 32 + m2 * 16 + fg * 4 + r;
        const int e = wih * 32 + n2 * 16 + fr;
        cp[d * 64 + e] = acc2[m2][n2][r];
      }
  // reduce + write per-channel sumexp partial
  if (wch == 0) {
    #pragma unroll
    for (int t = 0; t < 16; ++t) {
      float s = srun[t];
      s += __shfl_xor(s, 1); s += __shfl_xor(s, 2);
      s += __shfl_xor(s, 4); s += __shfl_xor(s, 8);
      if (fr == 0) sred[wih][(t >> 2) * 16 + fg * 4 + (t & 3)] = s;
    }
  }
  __syncthreads();
  if (tid < 64)
    s_part[(i64)((b * 8 + h) * 8 + chunk) * 64 + tid] = sred[0][tid] + sred[1][tid];
}

// ---------------- K5: merge chunk partials -> ctxh fp16 [bh][e][d] ---------
__global__ __launch_bounds__(256) void merge_kernel(const float* __restrict__ part,
                                                    const float* __restrict__ s_part,
                                                    short* __restrict__ ctxh) {
  const int bh = blockIdx.x, t = threadIdx.x;
  const int e = t & 63, db = t >> 6;
  const float* p = part + (i64)bh * 8 * 4096;
  const float* sp = s_part + (i64)bh * 8 * 64;
  #pragma unroll 4
  for (int dd = 0; dd < 16; ++dd) {
    const int d = db * 16 + dd;
    float s = 0.f, c = 0.f;
    #pragma unroll
    for (int k = 0; k < 8; ++k) {
      s += sp[k * 64 + d];
      c += p[k * 4096 + d * 64 + e];
    }
    ctxh[(i64)bh * 4096 + e * 64 + d] = f2h(c / s);
  }
}

// ---------------- K6: fused q GEMM + softmax + PV + GELU -> out2 -----------
// grid (NS/128, 8 h, 16 b). M=64 d x N=128 px, K=256.
__global__ __launch_bounds__(256) void qpv_kernel(const short* __restrict__ wh,
                                                  const short* __restrict__ fmapT,
                                                  const short* __restrict__ ctxh,
                                                  short* __restrict__ out2, int NS) {
  __shared__ short Xs[128 * LDX];
  __shared__ short qh[128 * LDQ];
  __shared__ float sden[2][128];
  const int h = blockIdx.y, b = blockIdx.z;
  const int i0 = blockIdx.x * 128;
  const int tid = threadIdx.x, lane = tid & 63, w = tid >> 6;
  const int fr = lane & 15, fg = lane >> 4;
  const int dh = w & 1, ih = w >> 1;
  const short* W = wh + (i64)(h * 64 + dh * 32) * 256;
  const short* Xg = fmapT + ((i64)b * NS + i0) * 256;

  f32x4 acc[2][4];
  #pragma unroll
  for (int m = 0; m < 2; ++m)
    #pragma unroll
    for (int n = 0; n < 4; ++n) acc[m][n] = (f32x4)0.f;

  const int r0 = tid >> 2, scq = tid & 3;
  const int sg0 = (scq ^ ((r0 >> 4) & 3)) * 8;
  const int sg1 = (scq ^ (((r0 + 64) >> 4) & 3)) * 8;

  for (int ks = 0; ks < 8; ++ks) {
    const int c0 = ks * 32;
    s16x8 sv0 = *(const s16x8*)&Xg[(i64)r0 * 256 + c0 + scq * 8];
    s16x8 sv1 = *(const s16x8*)&Xg[(i64)(r0 + 64) * 256 + c0 + scq * 8];
    __syncthreads();
    *(s16x8*)&Xs[r0 * LDX + sg0] = sv0;
    *(s16x8*)&Xs[(r0 + 64) * LDX + sg1] = sv1;
    __syncthreads();
    s16x8 a[2], bfr[4];
    #pragma unroll
    for (int m = 0; m < 2; ++m)
      a[m] = *(const s16x8*)&W[(i64)(m * 16 + fr) * 256 + c0 + fg * 8];
    #pragma unroll
    for (int n = 0; n < 4; ++n)
      bfr[n] = *(const s16x8*)&Xs[(ih * 64 + n * 16 + fr) * LDX + ((fg ^ (n & 3)) * 8)];
    #pragma unroll
    for (int m = 0; m < 2; ++m)
      #pragma unroll
      for (int n = 0; n < 4; ++n)
        acc[m][n] = MF(a[m], bfr[n], acc[m][n]);
  }
  // exp + per-pixel denominator across d (2 waves x 32 d)
  #pragma unroll
  for (int n = 0; n < 4; ++n) {
    float s = 0.f;
    #pragma unroll
    for (int m = 0; m < 2; ++m)
      #pragma unroll
      for (int r = 0; r < 4; ++r) {
        float e = __expf(acc[m][n][r]);
        acc[m][n][r] = e;
        s += e;
      }
    s += __shfl_xor(s, 16);
    s += __shfl_xor(s, 32);
    if (fg == 0) sden[dh][ih * 64 + n * 16 + fr] = s;
  }
  __syncthreads();
  if (tid < 128) sden[0][tid] += sden[1][tid];
  __syncthreads();
  // qhat -> LDS [px][d] fp16 (u64-packed 4-d chunks)
  #pragma unroll
  for (int n = 0; n < 4; ++n) {
    const int il = ih * 64 + n * 16 + fr;
    const float rs = 0.125f / sden[0][il];
    #pragma unroll
    for (int m = 0; m < 2; ++m) {
      const int d0 = dh * 32 + m * 16 + fg * 4;
      unsigned lo = (unsigned short)f2h(acc[m][n][0] * rs) |
                    ((unsigned)(unsigned short)f2h(acc[m][n][1] * rs) << 16);
      unsigned hi = (unsigned short)f2h(acc[m][n][2] * rs) |
                    ((unsigned)(unsigned short)f2h(acc[m][n][3] * rs) << 16);
      *(uint2*)&qh[il * LDQ + d0] = make_uint2(lo, hi);
    }
  }
  __syncthreads();
  // PV: out2[e][px] = sum_d ctx[e][d] * qhat[px][d]
  f32x4 acc3[2][4];
  #pragma unroll
  for (int m = 0; m < 2; ++m)
    #pragma unroll
    for (int n = 0; n < 4; ++n) acc3[m][n] = (f32x4)0.f;
  const i64 cbase = (i64)(b * 8 + h) * 4096;
  #pragma unroll
  for (int k2 = 0; k2 < 2; ++k2) {
    s16x8 a2[2], b2[4];
    #pragma unroll
    for (int m2 = 0; m2 < 2; ++m2)
      a2[m2] = *(const s16x8*)&ctxh[cbase + (i64)(dh * 32 + m2 * 16 + fr) * 64 + k2 * 32 + fg * 8];
    #pragma unroll
    for (int n2 = 0; n2 < 4; ++n2)
      b2[n2] = *(const s16x8*)&qh[(ih * 64 + n2 * 16 + fr) * LDQ + k2 * 32 + fg * 8];
    #pragma unroll
    for (int m2 = 0; m2 < 2; ++m2)
      #pragma unroll
      for (int n2 = 0; n2 < 4; ++n2)
        acc3[m2][n2] = MF(a2[m2], b2[n2], acc3[m2][n2]);
  }
  __syncthreads();   // qh reads done; reuse as transpose buffer
  // GELU + fp16, into qh as [px][e]
  #pragma unroll
  for (int m2 = 0; m2 < 2; ++m2)
    #pragma unroll
    for (int n2 = 0; n2 < 4; ++n2) {
      const int px = ih * 64 + n2 * 16 + fr;
      const int e0 = dh * 32 + m2 * 16 + fg * 4;
      float g[4];
      #pragma unroll
      for (int r = 0; r < 4; ++r) {
        float v = acc3[m2][n2][r];
        g[r] = 0.5f * v * (1.0f + erff(v * 0.70710678118654752f));
      }
      unsigned lo = (unsigned short)f2h(g[0]) | ((unsigned)(unsigned short)f2h(g[1]) << 16);
      unsigned hi = (unsigned short)f2h(g[2]) | ((unsigned)(unsigned short)f2h(g[3]) << 16);
      *(uint2*)&qh[px * LDQ + e0] = make_uint2(lo, hi);
    }
  __syncthreads();
  // coalesced out2 store: [b][px][512ch]
  {
    const int px = tid >> 1, half = tid & 1;
    short* op = out2 + ((i64)b * NS + i0 + px) * 512 + h * 64 + half * 32;
    #pragma unroll
    for (int j = 0; j < 4; ++j)
      *(uint4*)&op[j * 8] = *(const uint4*)&qh[px * LDQ + half * 32 + j * 8];
  }
}

// ---------------- K7: out = Wout @ gelu-out2 + bout ------------------------
// grid (NS/128, 4 og, 16 b). M=64 o x N=128 px, K=512.
__global__ __launch_bounds__(256) void wout_kernel(const short* __restrict__ wh,
                                                   const short* __restrict__ out2,
                                                   const float* __restrict__ bout,
                                                   float* __restrict__ Y,
                                                   int pxbase, int NS) {
  __shared__ short Xs[128 * LDX];
  const int og = blockIdx.y, b = blockIdx.z;
  const int i0 = blockIdx.x * 128;
  const int tid = threadIdx.x, lane = tid & 63, w = tid >> 6;
  const int fr = lane & 15, fg = lane >> 4;
  const int oh = w & 1, ih = w >> 1;
  const short* W = wh + 393216 + (i64)(og * 64 + oh * 32) * 512;
  const short* Xg = out2 + ((i64)b * NS + i0) * 512;

  f32x4 acc[2][4];
  #pragma unroll
  for (int m = 0; m < 2; ++m)
    #pragma unroll
    for (int n = 0; n < 4; ++n) acc[m][n] = (f32x4)0.f;

  const int r0 = tid >> 2, scq = tid & 3;
  const int sg0 = (scq ^ ((r0 >> 4) & 3)) * 8;
  const int sg1 = (scq ^ (((r0 + 64) >> 4) & 3)) * 8;

  for (int ks = 0; ks < 16; ++ks) {
    const int c0 = ks * 32;
    s16x8 sv0 = *(const s16x8*)&Xg[(i64)r0 * 512 + c0 + scq * 8];
    s16x8 sv1 = *(const s16x8*)&Xg[(i64)(r0 + 64) * 512 + c0 + scq * 8];
    __syncthreads();
    *(s16x8*)&Xs[r0 * LDX + sg0] = sv0;
    *(s16x8*)&Xs[(r0 + 64) * LDX + sg1] = sv1;
    __syncthreads();
    s16x8 a[2], bfr[4];
    #pragma unroll
    for (int m = 0; m < 2; ++m)
      a[m] = *(const s16x8*)&W[(i64)(m * 16 + fr) * 512 + c0 + fg * 8];
    #pragma unroll
    for (int n = 0; n < 4; ++n)
      bfr[n] = *(const s16x8*)&Xs[(ih * 64 + n * 16 + fr) * LDX + ((fg ^ (n & 3)) * 8)];
    #pragma unroll
    for (int m = 0; m < 2; ++m)
      #pragma unroll
      for (int n = 0; n < 4; ++n)
        acc[m][n] = MF(a[m], bfr[n], acc[m][n]);
  }
  #pragma unroll
  for (int m = 0; m < 2; ++m)
    #pragma unroll
    for (int r = 0; r < 4; ++r) {
      const int o = og * 64 + oh * 32 + m * 16 + fg * 4 + r;
      const float bv = bout[o];
      #pragma unroll
      for (int n = 0; n < 4; ++n)
        Y[(i64)(b * 256 + o) * NPIX + pxbase + i0 + ih * 64 + n * 16 + fr] =
            acc[m][n][r] + bv;
    }
}

// ---------------------------------------------------------------------------
extern "C" void kernel_launch(void* const* d_in, const int* in_sizes, int n_in,
                              void* d_out, int out_size, void* d_ws, size_t ws_size,
                              hipStream_t stream) {
  const float* fmap = (const float*)d_in[0];
  const float* Wq   = (const float*)d_in[1];
  const float* Wdw  = (const float*)d_in[2];
  const float* Wpw  = (const float*)d_in[3];
  const float* Wout = (const float*)d_in[4];
  const float* bout = (const float*)d_in[5];
  float* out = (float*)d_out;
  float* dw  = out;   // d_out hosts dw fp32 (dead before wout writes)

  // ws layout (bytes):
  //   wh       [0,         1048576)
  //   s_part   [1048576,   1310720)    128bh x 8 x 64 fp32
  //   ctx_part [1310720,   18087936)   128bh x 8 x 64 x 64 fp32
  //   ctxh     [18087936,  19136512)   128bh x 64e x 64d fp16
  //   dwT      [19136512,  52690944)   [b][4096][256] fp16
  //   fmapT    [52690944,  +33.5MB/S)  [b][NS][256] fp16 (per-slice)
  //   out2     [...,       +67MB/S)    [b][NS][512] fp16
  char* ws = (char*)d_ws;
  short* wh       = (short*)(ws);
  float* s_part   = (float*)(ws + 1048576);
  float* ctx_part = (float*)(ws + 1310720);
  short* ctxh     = (short*)(ws + 18087936);
  short* dwT      = (short*)(ws + 19136512);

  const i64 FM_OFF = 52690944;
  i64 avail = (i64)ws_size - FM_OFF;
  int S;
  if      (avail >= 100663296) S = 1;
  else if (avail >=  50331648) S = 2;
  else if (avail >=  25165824) S = 4;
  else if (avail >=  12582912) S = 8;
  else                         S = 16;
  const int NS = NPIX / S;
  short* fmapT = (short*)(ws + FM_OFF);
  short* out2  = fmapT + (i64)16 * NS * 256;

  dwconv_kernel<<<16 * 256 * 4096 / 256, 256, 0, stream>>>(fmap, Wdw, dw);
  wprep_kernel<<<2048, 256, 0, stream>>>(Wq, Wpw, Wout, wh);
  tcvt_kernel<<<dim3(16, 4, 16), 256, 0, stream>>>(dw, dwT, 0, NPIX);
  ctx_kernel<<<dim3(8, 8, 16), 256, 0, stream>>>(wh, dwT, ctx_part, s_part);
  merge_kernel<<<128, 256, 0, stream>>>(ctx_part, s_part, ctxh);
  for (int s = 0; s < S; ++s) {
    tcvt_kernel<<<dim3(NS / 256, 4, 16), 256, 0, stream>>>(fmap, fmapT, s * NS, NS);
    qpv_kernel<<<dim3(NS / 128, 8, 16), 256, 0, stream>>>(wh, fmapT, ctxh, out2, NS);
    wout_kernel<<<dim3(NS / 128, 4, 16), 256, 0, stream>>>(wh, out2, bout, out, s * NS, NS);
  }
}

// Round 6
// 365.336 us; speedup vs baseline: 4.3150x; 1.1661x over previous
//
#include <hip/hip_runtime.h>
#include <math.h>

// ---------------------------------------------------------------------------
// LinearAttention: B=16, DIM=256, H=W=64 (n=4096), HEADS=8, DH=64, INNER=512
// Round 6: ctx GEMM1 operand swap (C=[px][ch] -> packed uint2 kh/vv writes,
// kills the 7.3M scalar-write bank conflicts), BK=64 everywhere (half the
// barriers, 32 MFMA per barrier window), ws phase-aliasing (min 53 MB).
// ---------------------------------------------------------------------------

static constexpr int NPIX = 4096;
typedef long long i64;
typedef __attribute__((ext_vector_type(8))) short s16x8;
typedef __attribute__((ext_vector_type(8))) _Float16 f16x8;
typedef __attribute__((ext_vector_type(4))) float f32x4;

__device__ inline f32x4 MF(s16x8 a, s16x8 b, f32x4 c) {
  return __builtin_amdgcn_mfma_f32_16x16x32_f16(
      __builtin_bit_cast(f16x8, a), __builtin_bit_cast(f16x8, b), c, 0, 0, 0);
}
__device__ inline short f2h(float x) {
  return __builtin_bit_cast(short, (_Float16)x);
}
__device__ inline unsigned pk2(float a, float b) {
  return (unsigned)(unsigned short)f2h(a) | ((unsigned)(unsigned short)f2h(b) << 16);
}

#define LDX 72    // Xs row stride in shorts (64 c + 8 pad, 144B)
#define LDK 136   // kh/vv row stride in shorts (128 px + 8 pad, 272B)
#define LDQ 72    // qh row stride in shorts (64 + 8 pad, 144B)

// ---------------- K1: depthwise 3x3, pad 1 (fp32 -> d_out) -----------------
__global__ __launch_bounds__(256) void dwconv_kernel(const float* __restrict__ fmap,
                                                     const float* __restrict__ Wdw,
                                                     float* __restrict__ dw) {
  i64 p = (i64)blockIdx.x * 256 + threadIdx.x;
  int y = (int)(p & 63);
  int x = (int)((p >> 6) & 63);
  int c = (int)((p >> 12) & 255);
  const float* img = fmap + (p >> 12) * (i64)NPIX;
  const float* w = Wdw + c * 9;
  float s = 0.f;
  #pragma unroll
  for (int dx = -1; dx <= 1; ++dx) {
    int xx = x + dx;
    if ((unsigned)xx < 64u) {
      #pragma unroll
      for (int dy = -1; dy <= 1; ++dy) {
        int yy = y + dy;
        if ((unsigned)yy < 64u)
          s = fmaf(w[(dx + 1) * 3 + (dy + 1)], img[xx * 64 + yy], s);
      }
    }
  }
  dw[p] = s;
}

// ---------------- K2: weights -> fp16 --------------------------------------
// wh (shorts): Wq [0,131072) | Wpw [131072,393216) | Wout [393216,524288)
__global__ __launch_bounds__(256) void wprep_kernel(const float* __restrict__ Wq,
                                                    const float* __restrict__ Wpw,
                                                    const float* __restrict__ Wout,
                                                    short* __restrict__ wh) {
  int i = blockIdx.x * 256 + threadIdx.x;
  float v;
  if (i < 131072) v = Wq[i];
  else if (i < 393216) v = Wpw[i - 131072];
  else v = Wout[i - 393216];
  wh[i] = f2h(v);
}

// ---------------- K3: transpose+convert fp32 [c][px] -> fp16 [px][c] -------
__global__ __launch_bounds__(256) void tcvt_kernel(const float* __restrict__ src,
                                                   short* __restrict__ dst,
                                                   int src_px0, int nsl) {
  __shared__ short T[64 * 260];
  const int pxt = blockIdx.x * 256, ct = blockIdx.y * 64, b = blockIdx.z;
  const int t = threadIdx.x;
  const int pxq = t & 63, cl = t >> 6;
  const float* sp = src + (i64)(b * 256 + ct) * NPIX + src_px0 + pxt;
  #pragma unroll
  for (int cc = 0; cc < 16; ++cc) {
    const int c = cl + cc * 4;
    f32x4 v = *(const f32x4*)&sp[(i64)c * NPIX + pxq * 4];
    *(uint2*)&T[c * 260 + pxq * 4] = make_uint2(pk2(v[0], v[1]), pk2(v[2], v[3]));
  }
  __syncthreads();
  short arr[64];
  #pragma unroll
  for (int c = 0; c < 64; ++c) arr[c] = T[c * 260 + t];
  short* dp = dst + ((i64)b * nsl + pxt + t) * 256 + ct;
  #pragma unroll
  for (int j = 0; j < 8; ++j)
    *(uint4*)&dp[j * 8] = *(const uint4*)&arr[j * 8];
}

// ---------------- K4: fused k/v GEMM + exp + ctx partial -------------------
// grid (8 chunks of 512 px, 8 h, 16 b). Per it (4 its): GEMM1 computes
// C[128 px][64 ch] per wave-quadrant (A = X tile, B = W), exp on k-half,
// packed uint2 writes into kh/vv [ch][px], GEMM2 ctx += kh . vv^T.
__global__ __launch_bounds__(256) void ctx_kernel(const short* __restrict__ wh,
                                                  const short* __restrict__ dwT,
                                                  float* __restrict__ ctx_part,
                                                  float* __restrict__ s_part) {
  __shared__ short Xs[128 * LDX];
  __shared__ short kh[64 * LDK];
  __shared__ short vv[64 * LDK];
  const int chunk = blockIdx.x, h = blockIdx.y, b = blockIdx.z;
  const int tid = threadIdx.x, lane = tid & 63, w = tid >> 6;
  const int fr = lane & 15, fg = lane >> 4;
  const int wcv = w & 1, wpx = w >> 1;     // wcv: k/v half; wpx: px half
  const int wrow0 = (wcv ? 512 : 0) + h * 64;
  const short* W = wh + 131072 + (i64)wrow0 * 256;
  const short* Xg = dwT + ((i64)b * NPIX + chunk * 512) * 256;

  f32x4 acc2[2][2];
  #pragma unroll
  for (int m = 0; m < 2; ++m)
    #pragma unroll
    for (int n = 0; n < 2; ++n) acc2[m][n] = (f32x4)0.f;
  float srun[4] = {0.f, 0.f, 0.f, 0.f};

  const int r0 = tid >> 3, scq = tid & 7;  // staging: 32 rows x 8 col-groups

  for (int it = 0; it < 4; ++it) {
    f32x4 acc1[4][4];
    #pragma unroll
    for (int m = 0; m < 4; ++m)
      #pragma unroll
      for (int n = 0; n < 4; ++n) acc1[m][n] = (f32x4)0.f;

    for (int ks = 0; ks < 4; ++ks) {       // BK = 64
      const int c0 = ks * 64;
      s16x8 sv[4];
      #pragma unroll
      for (int j = 0; j < 4; ++j)
        sv[j] = *(const s16x8*)&Xg[(i64)(it * 128 + r0 + j * 32) * 256 + c0 + scq * 8];
      __syncthreads();
      #pragma unroll
      for (int j = 0; j < 4; ++j) {
        const int r = r0 + j * 32;
        Xs[0] = Xs[0];  // no-op
        *(s16x8*)&Xs[r * LDX + ((scq ^ ((r >> 4) & 7)) * 8)] = sv[j];
      }
      __syncthreads();
      #pragma unroll
      for (int k2 = 0; k2 < 2; ++k2) {
        s16x8 a[4], bb[4];
        #pragma unroll
        for (int m = 0; m < 4; ++m) {
          const int px = wpx * 64 + m * 16 + fr;
          a[m] = *(const s16x8*)&Xs[px * LDX + (((k2 * 4 + fg) ^ (wpx * 4 + m)) & 7) * 8];
        }
        #pragma unroll
        for (int n = 0; n < 4; ++n)
          bb[n] = *(const s16x8*)&W[(i64)(n * 16 + fr) * 256 + c0 + k2 * 32 + fg * 8];
        #pragma unroll
        for (int m = 0; m < 4; ++m)
          #pragma unroll
          for (int n = 0; n < 4; ++n)
            acc1[m][n] = MF(a[m], bb[n], acc1[m][n]);
      }
    }
    // k-half: exp (no max-sub; values bounded), per-channel running sums
    if (wcv == 0) {
      #pragma unroll
      for (int m = 0; m < 4; ++m)
        #pragma unroll
        for (int n = 0; n < 4; ++n)
          #pragma unroll
          for (int r = 0; r < 4; ++r) {
            float e = __expf(acc1[m][n][r]);
            acc1[m][n][r] = e;
            srun[n] += e;
          }
    }
    // packed writes: lane holds px {pg*8+(fg&1)*4 .. +3} of ch = n*16+fr
    {
      short* dst = wcv ? vv : kh;
      #pragma unroll
      for (int m = 0; m < 4; ++m)
        #pragma unroll
        for (int n = 0; n < 4; ++n) {
          const int ch = n * 16 + fr;
          const int pg = wpx * 8 + m * 2 + (fg >> 1);
          const int col = ((pg ^ (fr & 3)) * 8) + (fg & 1) * 4;
          *(uint2*)&dst[ch * LDK + col] =
              make_uint2(pk2(acc1[m][n][0], acc1[m][n][1]),
                         pk2(acc1[m][n][2], acc1[m][n][3]));
        }
    }
    __syncthreads();
    // GEMM2: ctx[d][e] += sum_px kh[d][px] * vv[e][px]; quadrant (wcv, wpx)
    #pragma unroll
    for (int k2 = 0; k2 < 4; ++k2) {
      const int colg = (((k2 * 4 + fg) ^ (fr & 3)) & 15) * 8;
      s16x8 a2[2], b2[2];
      #pragma unroll
      for (int m2 = 0; m2 < 2; ++m2)
        a2[m2] = *(const s16x8*)&kh[(wcv * 32 + m2 * 16 + fr) * LDK + colg];
      #pragma unroll
      for (int n2 = 0; n2 < 2; ++n2)
        b2[n2] = *(const s16x8*)&vv[(wpx * 32 + n2 * 16 + fr) * LDK + colg];
      #pragma unroll
      for (int m2 = 0; m2 < 2; ++m2)
        #pragma unroll
        for (int n2 = 0; n2 < 2; ++n2)
          acc2[m2][n2] = MF(a2[m2], b2[n2], acc2[m2][n2]);
    }
    __syncthreads();   // kh/vv consumed before next it overwrites
  }
  // write ctx partial [d][e]
  float* cp = ctx_part + (i64)((b * 8 + h) * 8 + chunk) * 4096;
  #pragma unroll
  for (int m2 = 0; m2 < 2; ++m2)
    #pragma unroll
    for (int n2 = 0; n2 < 2; ++n2)
      #pragma unroll
      for (int r = 0; r < 4; ++r) {
        const int d = wcv * 32 + m2 * 16 + fg * 4 + r;
        const int e = wpx * 32 + n2 * 16 + fr;
        cp[d * 64 + e] = acc2[m2][n2][r];
      }
  // per-channel sumexp: reduce over fg lanes, stash in kh (dead), emit
  float* sredp = (float*)kh;
  if (wcv == 0) {
    #pragma unroll
    for (int n = 0; n < 4; ++n) {
      float s = srun[n];
      s += __shfl_xor(s, 16);
      s += __shfl_xor(s, 32);
      if (fg == 0) sredp[wpx * 64 + n * 16 + fr] = s;
    }
  }
  __syncthreads();
  if (tid < 64)
    s_part[(i64)((b * 8 + h) * 8 + chunk) * 64 + tid] = sredp[tid] + sredp[64 + tid];
}

// ---------------- K5: merge chunk partials -> ctxh fp16 [bh][e][d] ---------
__global__ __launch_bounds__(256) void merge_kernel(const float* __restrict__ part,
                                                    const float* __restrict__ s_part,
                                                    short* __restrict__ ctxh) {
  const int bh = blockIdx.x, t = threadIdx.x;
  const int e = t & 63, db = t >> 6;
  const float* p = part + (i64)bh * 8 * 4096;
  const float* sp = s_part + (i64)bh * 8 * 64;
  #pragma unroll 4
  for (int dd = 0; dd < 16; ++dd) {
    const int d = db * 16 + dd;
    float s = 0.f, c = 0.f;
    #pragma unroll
    for (int k = 0; k < 8; ++k) {
      s += sp[k * 64 + d];
      c += p[k * 4096 + d * 64 + e];
    }
    ctxh[(i64)bh * 4096 + e * 64 + d] = f2h(c / s);
  }
}

// ---------------- K6: fused q GEMM + softmax + PV + GELU -> out2 -----------
// grid (NS/128, 8 h, 16 b). M=64 d x N=128 px, K=256 (BK=64).
__global__ __launch_bounds__(256) void qpv_kernel(const short* __restrict__ wh,
                                                  const short* __restrict__ fmapT,
                                                  const short* __restrict__ ctxh,
                                                  short* __restrict__ out2, int NS) {
  __shared__ short Xs[128 * LDX];
  __shared__ short qh[128 * LDQ];
  __shared__ float sden[2][128];
  const int h = blockIdx.y, b = blockIdx.z;
  const int i0 = blockIdx.x * 128;
  const int tid = threadIdx.x, lane = tid & 63, w = tid >> 6;
  const int fr = lane & 15, fg = lane >> 4;
  const int dh = w & 1, ih = w >> 1;
  const short* W = wh + (i64)(h * 64 + dh * 32) * 256;
  const short* Xg = fmapT + ((i64)b * NS + i0) * 256;

  f32x4 acc[2][4];
  #pragma unroll
  for (int m = 0; m < 2; ++m)
    #pragma unroll
    for (int n = 0; n < 4; ++n) acc[m][n] = (f32x4)0.f;

  const int r0 = tid >> 3, scq = tid & 7;

  for (int ks = 0; ks < 4; ++ks) {         // BK = 64
    const int c0 = ks * 64;
    s16x8 sv[4];
    #pragma unroll
    for (int j = 0; j < 4; ++j)
      sv[j] = *(const s16x8*)&Xg[(i64)(r0 + j * 32) * 256 + c0 + scq * 8];
    __syncthreads();
    #pragma unroll
    for (int j = 0; j < 4; ++j) {
      const int r = r0 + j * 32;
      *(s16x8*)&Xs[r * LDX + ((scq ^ ((r >> 4) & 7)) * 8)] = sv[j];
    }
    __syncthreads();
    #pragma unroll
    for (int k2 = 0; k2 < 2; ++k2) {
      s16x8 a[2], bfr[4];
      #pragma unroll
      for (int m = 0; m < 2; ++m)
        a[m] = *(const s16x8*)&W[(i64)(m * 16 + fr) * 256 + c0 + k2 * 32 + fg * 8];
      #pragma unroll
      for (int n = 0; n < 4; ++n) {
        const int px = ih * 64 + n * 16 + fr;
        bfr[n] = *(const s16x8*)&Xs[px * LDX + (((k2 * 4 + fg) ^ (ih * 4 + n)) & 7) * 8];
      }
      #pragma unroll
      for (int m = 0; m < 2; ++m)
        #pragma unroll
        for (int n = 0; n < 4; ++n)
          acc[m][n] = MF(a[m], bfr[n], acc[m][n]);
    }
  }
  // exp + per-pixel denominator across d (2 waves x 32 d)
  #pragma unroll
  for (int n = 0; n < 4; ++n) {
    float s = 0.f;
    #pragma unroll
    for (int m = 0; m < 2; ++m)
      #pragma unroll
      for (int r = 0; r < 4; ++r) {
        float e = __expf(acc[m][n][r]);
        acc[m][n][r] = e;
        s += e;
      }
    s += __shfl_xor(s, 16);
    s += __shfl_xor(s, 32);
    if (fg == 0) sden[dh][ih * 64 + n * 16 + fr] = s;
  }
  __syncthreads();
  if (tid < 128) sden[0][tid] += sden[1][tid];
  __syncthreads();
  // qhat -> LDS [px][d] fp16 (uint2-packed 4-d chunks)
  #pragma unroll
  for (int n = 0; n < 4; ++n) {
    const int il = ih * 64 + n * 16 + fr;
    const float rs = 0.125f / sden[0][il];
    #pragma unroll
    for (int m = 0; m < 2; ++m) {
      const int d0 = dh * 32 + m * 16 + fg * 4;
      *(uint2*)&qh[il * LDQ + d0] =
          make_uint2(pk2(acc[m][n][0] * rs, acc[m][n][1] * rs),
                     pk2(acc[m][n][2] * rs, acc[m][n][3] * rs));
    }
  }
  __syncthreads();
  // PV: out2[e][px] = sum_d ctx[e][d] * qhat[px][d]
  f32x4 acc3[2][4];
  #pragma unroll
  for (int m = 0; m < 2; ++m)
    #pragma unroll
    for (int n = 0; n < 4; ++n) acc3[m][n] = (f32x4)0.f;
  const i64 cbase = (i64)(b * 8 + h) * 4096;
  #pragma unroll
  for (int k2 = 0; k2 < 2; ++k2) {
    s16x8 a2[2], b2[4];
    #pragma unroll
    for (int m2 = 0; m2 < 2; ++m2)
      a2[m2] = *(const s16x8*)&ctxh[cbase + (i64)(dh * 32 + m2 * 16 + fr) * 64 + k2 * 32 + fg * 8];
    #pragma unroll
    for (int n2 = 0; n2 < 4; ++n2)
      b2[n2] = *(const s16x8*)&qh[(ih * 64 + n2 * 16 + fr) * LDQ + k2 * 32 + fg * 8];
    #pragma unroll
    for (int m2 = 0; m2 < 2; ++m2)
      #pragma unroll
      for (int n2 = 0; n2 < 4; ++n2)
        acc3[m2][n2] = MF(a2[m2], b2[n2], acc3[m2][n2]);
  }
  __syncthreads();   // qh reads done; reuse as transpose buffer
  // GELU + fp16, into qh as [px][e]
  #pragma unroll
  for (int m2 = 0; m2 < 2; ++m2)
    #pragma unroll
    for (int n2 = 0; n2 < 4; ++n2) {
      const int px = ih * 64 + n2 * 16 + fr;
      const int e0 = dh * 32 + m2 * 16 + fg * 4;
      float g[4];
      #pragma unroll
      for (int r = 0; r < 4; ++r) {
        float v = acc3[m2][n2][r];
        g[r] = 0.5f * v * (1.0f + erff(v * 0.70710678118654752f));
      }
      *(uint2*)&qh[px * LDQ + e0] = make_uint2(pk2(g[0], g[1]), pk2(g[2], g[3]));
    }
  __syncthreads();
  // coalesced out2 store: [b][px][512ch]
  {
    const int px = tid >> 1, half = tid & 1;
    short* op = out2 + ((i64)b * NS + i0 + px) * 512 + h * 64 + half * 32;
    #pragma unroll
    for (int j = 0; j < 4; ++j)
      *(uint4*)&op[j * 8] = *(const uint4*)&qh[px * LDQ + half * 32 + j * 8];
  }
}

// ---------------- K7: out = Wout @ gelu-out2 + bout ------------------------
// grid (NS/128, 4 og, 16 b). M=64 o x N=128 px, K=512 (BK=64).
__global__ __launch_bounds__(256) void wout_kernel(const short* __restrict__ wh,
                                                   const short* __restrict__ out2,
                                                   const float* __restrict__ bout,
                                                   float* __restrict__ Y,
                                                   int pxbase, int NS) {
  __shared__ short Xs[128 * LDX];
  const int og = blockIdx.y, b = blockIdx.z;
  const int i0 = blockIdx.x * 128;
  const int tid = threadIdx.x, lane = tid & 63, w = tid >> 6;
  const int fr = lane & 15, fg = lane >> 4;
  const int oh = w & 1, ih = w >> 1;
  const short* W = wh + 393216 + (i64)(og * 64 + oh * 32) * 512;
  const short* Xg = out2 + ((i64)b * NS + i0) * 512;

  f32x4 acc[2][4];
  #pragma unroll
  for (int m = 0; m < 2; ++m)
    #pragma unroll
    for (int n = 0; n < 4; ++n) acc[m][n] = (f32x4)0.f;

  const int r0 = tid >> 3, scq = tid & 7;

  for (int ks = 0; ks < 8; ++ks) {         // BK = 64, K = 512
    const int c0 = ks * 64;
    s16x8 sv[4];
    #pragma unroll
    for (int j = 0; j < 4; ++j)
      sv[j] = *(const s16x8*)&Xg[(i64)(r0 + j * 32) * 512 + c0 + scq * 8];
    __syncthreads();
    #pragma unroll
    for (int j = 0; j < 4; ++j) {
      const int r = r0 + j * 32;
      *(s16x8*)&Xs[r * LDX + ((scq ^ ((r >> 4) & 7)) * 8)] = sv[j];
    }
    __syncthreads();
    #pragma unroll
    for (int k2 = 0; k2 < 2; ++k2) {
      s16x8 a[2], bfr[4];
      #pragma unroll
      for (int m = 0; m < 2; ++m)
        a[m] = *(const s16x8*)&W[(i64)(m * 16 + fr) * 512 + c0 + k2 * 32 + fg * 8];
      #pragma unroll
      for (int n = 0; n < 4; ++n) {
        const int px = ih * 64 + n * 16 + fr;
        bfr[n] = *(const s16x8*)&Xs[px * LDX + (((k2 * 4 + fg) ^ (ih * 4 + n)) & 7) * 8];
      }
      #pragma unroll
      for (int m = 0; m < 2; ++m)
        #pragma unroll
        for (int n = 0; n < 4; ++n)
          acc[m][n] = MF(a[m], bfr[n], acc[m][n]);
    }
  }
  #pragma unroll
  for (int m = 0; m < 2; ++m)
    #pragma unroll
    for (int r = 0; r < 4; ++r) {
      const int o = og * 64 + oh * 32 + m * 16 + fg * 4 + r;
      const float bv = bout[o];
      #pragma unroll
      for (int n = 0; n < 4; ++n)
        Y[(i64)(b * 256 + o) * NPIX + pxbase + i0 + ih * 64 + n * 16 + fr] =
            acc[m][n][r] + bv;
    }
}

// ---------------------------------------------------------------------------
extern "C" void kernel_launch(void* const* d_in, const int* in_sizes, int n_in,
                              void* d_out, int out_size, void* d_ws, size_t ws_size,
                              hipStream_t stream) {
  const float* fmap = (const float*)d_in[0];
  const float* Wq   = (const float*)d_in[1];
  const float* Wdw  = (const float*)d_in[2];
  const float* Wpw  = (const float*)d_in[3];
  const float* Wout = (const float*)d_in[4];
  const float* bout = (const float*)d_in[5];
  float* out = (float*)d_out;
  float* dw  = out;   // d_out hosts dw fp32 (dead before wout writes)

  // ws layout (bytes), phase-aliased big region:
  //   wh       [0,       1048576)
  //   s_part   [1048576, 1572864)
  //   ctxh     [1572864, 2621440)
  //   BIG      [2621440, ...):
  //     phase1: ctx_part [2621440, 19398656)  (16.8 MB)
  //             dwT      [19398656, 52953088) (33.5 MB)
  //     phase2: fmapT    [2621440, +33.5MB/S)
  //             out2     [..,      +67MB/S)
  // min ws = 53 MB (phase1); S=1 needs 103.3 MB.
  char* ws = (char*)d_ws;
  short* wh       = (short*)(ws);
  float* s_part   = (float*)(ws + 1048576);
  short* ctxh     = (short*)(ws + 1572864);
  float* ctx_part = (float*)(ws + 2621440);
  short* dwT      = (short*)(ws + 19398656);

  i64 avail = (i64)ws_size - 2621440;
  const int S = (avail >= 100663296) ? 1 : 2;
  const int NS = NPIX / S;
  short* fmapT = (short*)(ws + 2621440);
  short* out2  = fmapT + (i64)16 * NS * 256;

  dwconv_kernel<<<16 * 256 * 4096 / 256, 256, 0, stream>>>(fmap, Wdw, dw);
  wprep_kernel<<<2048, 256, 0, stream>>>(Wq, Wpw, Wout, wh);
  tcvt_kernel<<<dim3(16, 4, 16), 256, 0, stream>>>(dw, dwT, 0, NPIX);
  ctx_kernel<<<dim3(8, 8, 16), 256, 0, stream>>>(wh, dwT, ctx_part, s_part);
  merge_kernel<<<128, 256, 0, stream>>>(ctx_part, s_part, ctxh);
  for (int s = 0; s < S; ++s) {
    tcvt_kernel<<<dim3(NS / 256, 4, 16), 256, 0, stream>>>(fmap, fmapT, s * NS, NS);
    qpv_kernel<<<dim3(NS / 128, 8, 16), 256, 0, stream>>>(wh, fmapT, ctxh, out2, NS);
    wout_kernel<<<dim3(NS / 128, 4, 16), 256, 0, stream>>>(wh, out2, bout, out, s * NS, NS);
  }
}

// Round 7
// 310.764 us; speedup vs baseline: 5.0728x; 1.1756x over previous
//
#include <hip/hip_runtime.h>
#include <math.h>

// ---------------------------------------------------------------------------
// LinearAttention: B=16, DIM=256, H=W=64 (n=4096), HEADS=8, DH=64, INNER=512
// Round 7: front-end fix. dwconv was issue-bound (118us, 9 scalar loads / 1
// output). Now: 4 y-outputs per thread via float4 taps (9 loads / 4 outputs),
// fp16 output written directly into d_out scratch (halves write + tcvt read).
// GEMM kernels unchanged from round 6.
// ---------------------------------------------------------------------------

static constexpr int NPIX = 4096;
typedef long long i64;
typedef __attribute__((ext_vector_type(8))) short s16x8;
typedef __attribute__((ext_vector_type(8))) _Float16 f16x8;
typedef __attribute__((ext_vector_type(4))) float f32x4;

__device__ inline f32x4 MF(s16x8 a, s16x8 b, f32x4 c) {
  return __builtin_amdgcn_mfma_f32_16x16x32_f16(
      __builtin_bit_cast(f16x8, a), __builtin_bit_cast(f16x8, b), c, 0, 0, 0);
}
__device__ inline short f2h(float x) {
  return __builtin_bit_cast(short, (_Float16)x);
}
__device__ inline unsigned pk2(float a, float b) {
  return (unsigned)(unsigned short)f2h(a) | ((unsigned)(unsigned short)f2h(b) << 16);
}

#define LDX 72    // Xs row stride in shorts (64 c + 8 pad, 144B)
#define LDK 136   // kh/vv row stride in shorts (128 px + 8 pad, 272B)
#define LDQ 72    // qh row stride in shorts (64 + 8 pad, 144B)

// ---------------- K1: depthwise 3x3, pad 1; 4 y/thread; fp16 out -----------
// thread -> (b, c, x, y-quad). output dwh [b*256+c][4096 px] fp16.
__global__ __launch_bounds__(256) void dwconv_kernel(const float* __restrict__ fmap,
                                                     const float* __restrict__ Wdw,
                                                     short* __restrict__ dwh) {
  i64 p4 = (i64)blockIdx.x * 256 + threadIdx.x;    // over 16*256*64*16
  const int yq = (int)(p4 & 15);
  const int x  = (int)((p4 >> 4) & 63);
  const int c  = (int)((p4 >> 10) & 255);
  const i64 bc = p4 >> 10;
  const float* img = fmap + bc * (i64)NPIX;
  const float* w = Wdw + c * 9;
  const int y0 = yq * 4;
  float a0 = 0.f, a1 = 0.f, a2 = 0.f, a3 = 0.f;
  #pragma unroll
  for (int dx = -1; dx <= 1; ++dx) {
    const int xx = x + dx;
    if ((unsigned)xx < 64u) {
      const float* row = img + xx * 64 + y0;
      const f32x4 v = *(const f32x4*)row;
      const float vm = (y0 > 0)  ? row[-1] : 0.f;
      const float vp = (y0 < 60) ? row[4]  : 0.f;
      const float wm = w[(dx + 1) * 3], wc = w[(dx + 1) * 3 + 1], wp = w[(dx + 1) * 3 + 2];
      a0 = fmaf(wm, vm,   fmaf(wc, v[0], fmaf(wp, v[1], a0)));
      a1 = fmaf(wm, v[0], fmaf(wc, v[1], fmaf(wp, v[2], a1)));
      a2 = fmaf(wm, v[1], fmaf(wc, v[2], fmaf(wp, v[3], a2)));
      a3 = fmaf(wm, v[2], fmaf(wc, v[3], fmaf(wp, vp,   a3)));
    }
  }
  *(uint2*)&dwh[bc * (i64)NPIX + x * 64 + y0] = make_uint2(pk2(a0, a1), pk2(a2, a3));
}

// ---------------- K2: weights -> fp16 --------------------------------------
// wh (shorts): Wq [0,131072) | Wpw [131072,393216) | Wout [393216,524288)
__global__ __launch_bounds__(256) void wprep_kernel(const float* __restrict__ Wq,
                                                    const float* __restrict__ Wpw,
                                                    const float* __restrict__ Wout,
                                                    short* __restrict__ wh) {
  int i = blockIdx.x * 256 + threadIdx.x;
  float v;
  if (i < 131072) v = Wq[i];
  else if (i < 393216) v = Wpw[i - 131072];
  else v = Wout[i - 393216];
  wh[i] = f2h(v);
}

// ---------------- K3a: transpose+convert fp32 [c][px] -> fp16 [px][c] ------
__global__ __launch_bounds__(256) void tcvt_kernel(const float* __restrict__ src,
                                                   short* __restrict__ dst,
                                                   int src_px0, int nsl) {
  __shared__ short T[64 * 260];
  const int pxt = blockIdx.x * 256, ct = blockIdx.y * 64, b = blockIdx.z;
  const int t = threadIdx.x;
  const int pxq = t & 63, cl = t >> 6;
  const float* sp = src + (i64)(b * 256 + ct) * NPIX + src_px0 + pxt;
  #pragma unroll
  for (int cc = 0; cc < 16; ++cc) {
    const int c = cl + cc * 4;
    f32x4 v = *(const f32x4*)&sp[(i64)c * NPIX + pxq * 4];
    *(uint2*)&T[c * 260 + pxq * 4] = make_uint2(pk2(v[0], v[1]), pk2(v[2], v[3]));
  }
  __syncthreads();
  short arr[64];
  #pragma unroll
  for (int c = 0; c < 64; ++c) arr[c] = T[c * 260 + t];
  short* dp = dst + ((i64)b * nsl + pxt + t) * 256 + ct;
  #pragma unroll
  for (int j = 0; j < 8; ++j)
    *(uint4*)&dp[j * 8] = *(const uint4*)&arr[j * 8];
}

// ---------------- K3b: transpose fp16 [c][px] -> fp16 [px][c] --------------
__global__ __launch_bounds__(256) void tcvt16_kernel(const short* __restrict__ src,
                                                     short* __restrict__ dst) {
  __shared__ short T[64 * 260];
  const int pxt = blockIdx.x * 256, ct = blockIdx.y * 64, b = blockIdx.z;
  const int t = threadIdx.x;
  const int pxq = t & 63, cl = t >> 6;
  const short* sp = src + (i64)(b * 256 + ct) * NPIX + pxt;
  #pragma unroll
  for (int cc = 0; cc < 16; ++cc) {
    const int c = cl + cc * 4;
    *(uint2*)&T[c * 260 + pxq * 4] = *(const uint2*)&sp[(i64)c * NPIX + pxq * 4];
  }
  __syncthreads();
  short arr[64];
  #pragma unroll
  for (int c = 0; c < 64; ++c) arr[c] = T[c * 260 + t];
  short* dp = dst + ((i64)b * NPIX + pxt + t) * 256 + ct;
  #pragma unroll
  for (int j = 0; j < 8; ++j)
    *(uint4*)&dp[j * 8] = *(const uint4*)&arr[j * 8];
}

// ---------------- K4: fused k/v GEMM + exp + ctx partial -------------------
// grid (8 chunks of 512 px, 8 h, 16 b). Per it (4 its): GEMM1 computes
// C[128 px][64 ch] per wave-quadrant (A = X tile, B = W), exp on k-half,
// packed uint2 writes into kh/vv [ch][px], GEMM2 ctx += kh . vv^T.
__global__ __launch_bounds__(256) void ctx_kernel(const short* __restrict__ wh,
                                                  const short* __restrict__ dwT,
                                                  float* __restrict__ ctx_part,
                                                  float* __restrict__ s_part) {
  __shared__ short Xs[128 * LDX];
  __shared__ short kh[64 * LDK];
  __shared__ short vv[64 * LDK];
  const int chunk = blockIdx.x, h = blockIdx.y, b = blockIdx.z;
  const int tid = threadIdx.x, lane = tid & 63, w = tid >> 6;
  const int fr = lane & 15, fg = lane >> 4;
  const int wcv = w & 1, wpx = w >> 1;     // wcv: k/v half; wpx: px half
  const int wrow0 = (wcv ? 512 : 0) + h * 64;
  const short* W = wh + 131072 + (i64)wrow0 * 256;
  const short* Xg = dwT + ((i64)b * NPIX + chunk * 512) * 256;

  f32x4 acc2[2][2];
  #pragma unroll
  for (int m = 0; m < 2; ++m)
    #pragma unroll
    for (int n = 0; n < 2; ++n) acc2[m][n] = (f32x4)0.f;
  float srun[4] = {0.f, 0.f, 0.f, 0.f};

  const int r0 = tid >> 3, scq = tid & 7;  // staging: 32 rows x 8 col-groups

  for (int it = 0; it < 4; ++it) {
    f32x4 acc1[4][4];
    #pragma unroll
    for (int m = 0; m < 4; ++m)
      #pragma unroll
      for (int n = 0; n < 4; ++n) acc1[m][n] = (f32x4)0.f;

    for (int ks = 0; ks < 4; ++ks) {       // BK = 64
      const int c0 = ks * 64;
      s16x8 sv[4];
      #pragma unroll
      for (int j = 0; j < 4; ++j)
        sv[j] = *(const s16x8*)&Xg[(i64)(it * 128 + r0 + j * 32) * 256 + c0 + scq * 8];
      __syncthreads();
      #pragma unroll
      for (int j = 0; j < 4; ++j) {
        const int r = r0 + j * 32;
        *(s16x8*)&Xs[r * LDX + ((scq ^ ((r >> 4) & 7)) * 8)] = sv[j];
      }
      __syncthreads();
      #pragma unroll
      for (int k2 = 0; k2 < 2; ++k2) {
        s16x8 a[4], bb[4];
        #pragma unroll
        for (int m = 0; m < 4; ++m) {
          const int px = wpx * 64 + m * 16 + fr;
          a[m] = *(const s16x8*)&Xs[px * LDX + (((k2 * 4 + fg) ^ (wpx * 4 + m)) & 7) * 8];
        }
        #pragma unroll
        for (int n = 0; n < 4; ++n)
          bb[n] = *(const s16x8*)&W[(i64)(n * 16 + fr) * 256 + c0 + k2 * 32 + fg * 8];
        #pragma unroll
        for (int m = 0; m < 4; ++m)
          #pragma unroll
          for (int n = 0; n < 4; ++n)
            acc1[m][n] = MF(a[m], bb[n], acc1[m][n]);
      }
    }
    // k-half: exp (no max-sub; values bounded), per-channel running sums
    if (wcv == 0) {
      #pragma unroll
      for (int m = 0; m < 4; ++m)
        #pragma unroll
        for (int n = 0; n < 4; ++n)
          #pragma unroll
          for (int r = 0; r < 4; ++r) {
            float e = __expf(acc1[m][n][r]);
            acc1[m][n][r] = e;
            srun[n] += e;
          }
    }
    // packed writes: lane holds px {pg*8+(fg&1)*4 .. +3} of ch = n*16+fr
    {
      short* dst = wcv ? vv : kh;
      #pragma unroll
      for (int m = 0; m < 4; ++m)
        #pragma unroll
        for (int n = 0; n < 4; ++n) {
          const int ch = n * 16 + fr;
          const int pg = wpx * 8 + m * 2 + (fg >> 1);
          const int col = ((pg ^ (fr & 3)) * 8) + (fg & 1) * 4;
          *(uint2*)&dst[ch * LDK + col] =
              make_uint2(pk2(acc1[m][n][0], acc1[m][n][1]),
                         pk2(acc1[m][n][2], acc1[m][n][3]));
        }
    }
    __syncthreads();
    // GEMM2: ctx[d][e] += sum_px kh[d][px] * vv[e][px]; quadrant (wcv, wpx)
    #pragma unroll
    for (int k2 = 0; k2 < 4; ++k2) {
      const int colg = (((k2 * 4 + fg) ^ (fr & 3)) & 15) * 8;
      s16x8 a2[2], b2[2];
      #pragma unroll
      for (int m2 = 0; m2 < 2; ++m2)
        a2[m2] = *(const s16x8*)&kh[(wcv * 32 + m2 * 16 + fr) * LDK + colg];
      #pragma unroll
      for (int n2 = 0; n2 < 2; ++n2)
        b2[n2] = *(const s16x8*)&vv[(wpx * 32 + n2 * 16 + fr) * LDK + colg];
      #pragma unroll
      for (int m2 = 0; m2 < 2; ++m2)
        #pragma unroll
        for (int n2 = 0; n2 < 2; ++n2)
          acc2[m2][n2] = MF(a2[m2], b2[n2], acc2[m2][n2]);
    }
    __syncthreads();   // kh/vv consumed before next it overwrites
  }
  // write ctx partial [d][e]
  float* cp = ctx_part + (i64)((b * 8 + h) * 8 + chunk) * 4096;
  #pragma unroll
  for (int m2 = 0; m2 < 2; ++m2)
    #pragma unroll
    for (int n2 = 0; n2 < 2; ++n2)
      #pragma unroll
      for (int r = 0; r < 4; ++r) {
        const int d = wcv * 32 + m2 * 16 + fg * 4 + r;
        const int e = wpx * 32 + n2 * 16 + fr;
        cp[d * 64 + e] = acc2[m2][n2][r];
      }
  // per-channel sumexp: reduce over fg lanes, stash in kh (dead), emit
  float* sredp = (float*)kh;
  if (wcv == 0) {
    #pragma unroll
    for (int n = 0; n < 4; ++n) {
      float s = srun[n];
      s += __shfl_xor(s, 16);
      s += __shfl_xor(s, 32);
      if (fg == 0) sredp[wpx * 64 + n * 16 + fr] = s;
    }
  }
  __syncthreads();
  if (tid < 64)
    s_part[(i64)((b * 8 + h) * 8 + chunk) * 64 + tid] = sredp[tid] + sredp[64 + tid];
}

// ---------------- K5: merge chunk partials -> ctxh fp16 [bh][e][d] ---------
__global__ __launch_bounds__(256) void merge_kernel(const float* __restrict__ part,
                                                    const float* __restrict__ s_part,
                                                    short* __restrict__ ctxh) {
  const int bh = blockIdx.x, t = threadIdx.x;
  const int e = t & 63, db = t >> 6;
  const float* p = part + (i64)bh * 8 * 4096;
  const float* sp = s_part + (i64)bh * 8 * 64;
  #pragma unroll 4
  for (int dd = 0; dd < 16; ++dd) {
    const int d = db * 16 + dd;
    float s = 0.f, c = 0.f;
    #pragma unroll
    for (int k = 0; k < 8; ++k) {
      s += sp[k * 64 + d];
      c += p[k * 4096 + d * 64 + e];
    }
    ctxh[(i64)bh * 4096 + e * 64 + d] = f2h(c / s);
  }
}

// ---------------- K6: fused q GEMM + softmax + PV + GELU -> out2 -----------
// grid (NS/128, 8 h, 16 b). M=64 d x N=128 px, K=256 (BK=64).
__global__ __launch_bounds__(256) void qpv_kernel(const short* __restrict__ wh,
                                                  const short* __restrict__ fmapT,
                                                  const short* __restrict__ ctxh,
                                                  short* __restrict__ out2, int NS) {
  __shared__ short Xs[128 * LDX];
  __shared__ short qh[128 * LDQ];
  __shared__ float sden[2][128];
  const int h = blockIdx.y, b = blockIdx.z;
  const int i0 = blockIdx.x * 128;
  const int tid = threadIdx.x, lane = tid & 63, w = tid >> 6;
  const int fr = lane & 15, fg = lane >> 4;
  const int dh = w & 1, ih = w >> 1;
  const short* W = wh + (i64)(h * 64 + dh * 32) * 256;
  const short* Xg = fmapT + ((i64)b * NS + i0) * 256;

  f32x4 acc[2][4];
  #pragma unroll
  for (int m = 0; m < 2; ++m)
    #pragma unroll
    for (int n = 0; n < 4; ++n) acc[m][n] = (f32x4)0.f;

  const int r0 = tid >> 3, scq = tid & 7;

  for (int ks = 0; ks < 4; ++ks) {         // BK = 64
    const int c0 = ks * 64;
    s16x8 sv[4];
    #pragma unroll
    for (int j = 0; j < 4; ++j)
      sv[j] = *(const s16x8*)&Xg[(i64)(r0 + j * 32) * 256 + c0 + scq * 8];
    __syncthreads();
    #pragma unroll
    for (int j = 0; j < 4; ++j) {
      const int r = r0 + j * 32;
      *(s16x8*)&Xs[r * LDX + ((scq ^ ((r >> 4) & 7)) * 8)] = sv[j];
    }
    __syncthreads();
    #pragma unroll
    for (int k2 = 0; k2 < 2; ++k2) {
      s16x8 a[2], bfr[4];
      #pragma unroll
      for (int m = 0; m < 2; ++m)
        a[m] = *(const s16x8*)&W[(i64)(m * 16 + fr) * 256 + c0 + k2 * 32 + fg * 8];
      #pragma unroll
      for (int n = 0; n < 4; ++n) {
        const int px = ih * 64 + n * 16 + fr;
        bfr[n] = *(const s16x8*)&Xs[px * LDX + (((k2 * 4 + fg) ^ (ih * 4 + n)) & 7) * 8];
      }
      #pragma unroll
      for (int m = 0; m < 2; ++m)
        #pragma unroll
        for (int n = 0; n < 4; ++n)
          acc[m][n] = MF(a[m], bfr[n], acc[m][n]);
    }
  }
  // exp + per-pixel denominator across d (2 waves x 32 d)
  #pragma unroll
  for (int n = 0; n < 4; ++n) {
    float s = 0.f;
    #pragma unroll
    for (int m = 0; m < 2; ++m)
      #pragma unroll
      for (int r = 0; r < 4; ++r) {
        float e = __expf(acc[m][n][r]);
        acc[m][n][r] = e;
        s += e;
      }
    s += __shfl_xor(s, 16);
    s += __shfl_xor(s, 32);
    if (fg == 0) sden[dh][ih * 64 + n * 16 + fr] = s;
  }
  __syncthreads();
  if (tid < 128) sden[0][tid] += sden[1][tid];
  __syncthreads();
  // qhat -> LDS [px][d] fp16 (uint2-packed 4-d chunks)
  #pragma unroll
  for (int n = 0; n < 4; ++n) {
    const int il = ih * 64 + n * 16 + fr;
    const float rs = 0.125f / sden[0][il];
    #pragma unroll
    for (int m = 0; m < 2; ++m) {
      const int d0 = dh * 32 + m * 16 + fg * 4;
      *(uint2*)&qh[il * LDQ + d0] =
          make_uint2(pk2(acc[m][n][0] * rs, acc[m][n][1] * rs),
                     pk2(acc[m][n][2] * rs, acc[m][n][3] * rs));
    }
  }
  __syncthreads();
  // PV: out2[e][px] = sum_d ctx[e][d] * qhat[px][d]
  f32x4 acc3[2][4];
  #pragma unroll
  for (int m = 0; m < 2; ++m)
    #pragma unroll
    for (int n = 0; n < 4; ++n) acc3[m][n] = (f32x4)0.f;
  const i64 cbase = (i64)(b * 8 + h) * 4096;
  #pragma unroll
  for (int k2 = 0; k2 < 2; ++k2) {
    s16x8 a2[2], b2[4];
    #pragma unroll
    for (int m2 = 0; m2 < 2; ++m2)
      a2[m2] = *(const s16x8*)&ctxh[cbase + (i64)(dh * 32 + m2 * 16 + fr) * 64 + k2 * 32 + fg * 8];
    #pragma unroll
    for (int n2 = 0; n2 < 4; ++n2)
      b2[n2] = *(const s16x8*)&qh[(ih * 64 + n2 * 16 + fr) * LDQ + k2 * 32 + fg * 8];
    #pragma unroll
    for (int m2 = 0; m2 < 2; ++m2)
      #pragma unroll
      for (int n2 = 0; n2 < 4; ++n2)
        acc3[m2][n2] = MF(a2[m2], b2[n2], acc3[m2][n2]);
  }
  __syncthreads();   // qh reads done; reuse as transpose buffer
  // GELU + fp16, into qh as [px][e]
  #pragma unroll
  for (int m2 = 0; m2 < 2; ++m2)
    #pragma unroll
    for (int n2 = 0; n2 < 4; ++n2) {
      const int px = ih * 64 + n2 * 16 + fr;
      const int e0 = dh * 32 + m2 * 16 + fg * 4;
      float g[4];
      #pragma unroll
      for (int r = 0; r < 4; ++r) {
        float v = acc3[m2][n2][r];
        g[r] = 0.5f * v * (1.0f + erff(v * 0.70710678118654752f));
      }
      *(uint2*)&qh[px * LDQ + e0] = make_uint2(pk2(g[0], g[1]), pk2(g[2], g[3]));
    }
  __syncthreads();
  // coalesced out2 store: [b][px][512ch]
  {
    const int px = tid >> 1, half = tid & 1;
    short* op = out2 + ((i64)b * NS + i0 + px) * 512 + h * 64 + half * 32;
    #pragma unroll
    for (int j = 0; j < 4; ++j)
      *(uint4*)&op[j * 8] = *(const uint4*)&qh[px * LDQ + half * 32 + j * 8];
  }
}

// ---------------- K7: out = Wout @ gelu-out2 + bout ------------------------
// grid (NS/128, 4 og, 16 b). M=64 o x N=128 px, K=512 (BK=64).
__global__ __launch_bounds__(256) void wout_kernel(const short* __restrict__ wh,
                                                   const short* __restrict__ out2,
                                                   const float* __restrict__ bout,
                                                   float* __restrict__ Y,
                                                   int pxbase, int NS) {
  __shared__ short Xs[128 * LDX];
  const int og = blockIdx.y, b = blockIdx.z;
  const int i0 = blockIdx.x * 128;
  const int tid = threadIdx.x, lane = tid & 63, w = tid >> 6;
  const int fr = lane & 15, fg = lane >> 4;
  const int oh = w & 1, ih = w >> 1;
  const short* W = wh + 393216 + (i64)(og * 64 + oh * 32) * 512;
  const short* Xg = out2 + ((i64)b * NS + i0) * 512;

  f32x4 acc[2][4];
  #pragma unroll
  for (int m = 0; m < 2; ++m)
    #pragma unroll
    for (int n = 0; n < 4; ++n) acc[m][n] = (f32x4)0.f;

  const int r0 = tid >> 3, scq = tid & 7;

  for (int ks = 0; ks < 8; ++ks) {         // BK = 64, K = 512
    const int c0 = ks * 64;
    s16x8 sv[4];
    #pragma unroll
    for (int j = 0; j < 4; ++j)
      sv[j] = *(const s16x8*)&Xg[(i64)(r0 + j * 32) * 512 + c0 + scq * 8];
    __syncthreads();
    #pragma unroll
    for (int j = 0; j < 4; ++j) {
      const int r = r0 + j * 32;
      *(s16x8*)&Xs[r * LDX + ((scq ^ ((r >> 4) & 7)) * 8)] = sv[j];
    }
    __syncthreads();
    #pragma unroll
    for (int k2 = 0; k2 < 2; ++k2) {
      s16x8 a[2], bfr[4];
      #pragma unroll
      for (int m = 0; m < 2; ++m)
        a[m] = *(const s16x8*)&W[(i64)(m * 16 + fr) * 512 + c0 + k2 * 32 + fg * 8];
      #pragma unroll
      for (int n = 0; n < 4; ++n) {
        const int px = ih * 64 + n * 16 + fr;
        bfr[n] = *(const s16x8*)&Xs[px * LDX + (((k2 * 4 + fg) ^ (ih * 4 + n)) & 7) * 8];
      }
      #pragma unroll
      for (int m = 0; m < 2; ++m)
        #pragma unroll
        for (int n = 0; n < 4; ++n)
          acc[m][n] = MF(a[m], bfr[n], acc[m][n]);
    }
  }
  #pragma unroll
  for (int m = 0; m < 2; ++m)
    #pragma unroll
    for (int r = 0; r < 4; ++r) {
      const int o = og * 64 + oh * 32 + m * 16 + fg * 4 + r;
      const float bv = bout[o];
      #pragma unroll
      for (int n = 0; n < 4; ++n)
        Y[(i64)(b * 256 + o) * NPIX + pxbase + i0 + ih * 64 + n * 16 + fr] =
            acc[m][n][r] + bv;
    }
}

// ---------------------------------------------------------------------------
extern "C" void kernel_launch(void* const* d_in, const int* in_sizes, int n_in,
                              void* d_out, int out_size, void* d_ws, size_t ws_size,
                              hipStream_t stream) {
  const float* fmap = (const float*)d_in[0];
  const float* Wq   = (const float*)d_in[1];
  const float* Wdw  = (const float*)d_in[2];
  const float* Wpw  = (const float*)d_in[3];
  const float* Wout = (const float*)d_in[4];
  const float* bout = (const float*)d_in[5];
  float* out = (float*)d_out;
  short* dwh = (short*)d_out;   // d_out hosts dw fp16 (32MB; dead before wout)

  // ws layout (bytes), phase-aliased big region:
  //   wh       [0,       1048576)
  //   s_part   [1048576, 1572864)
  //   ctxh     [1572864, 2621440)
  //   BIG      [2621440, ...):
  //     phase1: ctx_part [2621440, 19398656)  (16.8 MB)
  //             dwT      [19398656, 52953088) (33.5 MB)
  //     phase2: fmapT    [2621440, +33.5MB/S)
  //             out2     [..,      +67MB/S)
  // min ws = 53 MB (phase1); S=1 needs 103.3 MB.
  char* ws = (char*)d_ws;
  short* wh       = (short*)(ws);
  float* s_part   = (float*)(ws + 1048576);
  short* ctxh     = (short*)(ws + 1572864);
  float* ctx_part = (float*)(ws + 2621440);
  short* dwT      = (short*)(ws + 19398656);

  i64 avail = (i64)ws_size - 2621440;
  const int S = (avail >= 100663296) ? 1 : 2;
  const int NS = NPIX / S;
  short* fmapT = (short*)(ws + 2621440);
  short* out2  = fmapT + (i64)16 * NS * 256;

  dwconv_kernel<<<16384, 256, 0, stream>>>(fmap, Wdw, dwh);
  wprep_kernel<<<2048, 256, 0, stream>>>(Wq, Wpw, Wout, wh);
  tcvt16_kernel<<<dim3(16, 4, 16), 256, 0, stream>>>(dwh, dwT);
  ctx_kernel<<<dim3(8, 8, 16), 256, 0, stream>>>(wh, dwT, ctx_part, s_part);
  merge_kernel<<<128, 256, 0, stream>>>(ctx_part, s_part, ctxh);
  for (int s = 0; s < S; ++s) {
    tcvt_kernel<<<dim3(NS / 256, 4, 16), 256, 0, stream>>>(fmap, fmapT, s * NS, NS);
    qpv_kernel<<<dim3(NS / 128, 8, 16), 256, 0, stream>>>(wh, fmapT, ctxh, out2, NS);
    wout_kernel<<<dim3(NS / 128, 4, 16), 256, 0, stream>>>(wh, out2, bout, out, s * NS, NS);
  }
}

// Round 8
// 301.384 us; speedup vs baseline: 5.2306x; 1.0311x over previous
//
#include <hip/hip_runtime.h>
#include <math.h>

// ---------------------------------------------------------------------------
// LinearAttention: B=16, DIM=256, H=W=64 (n=4096), HEADS=8, DH=64, INNER=512
// Round 8: ctx/wout fixes from bank arithmetic + barrier halving.
//   - LDK=136 shorts => row stride ≡ 1 group (mod 8): natural bank rotation.
//     The old XOR ^(fr&3) on kh/vv BROKE it (4-way). Removed (reads+writes).
//   - Xs double-buffered in ctx & wout: 1 barrier/BK-step, prefetch hidden
//     under MFMA. ctx barriers 42 -> ~23, wout 16 -> 9.
//   - qpv unchanged (dbuf would cost a block/CU of occupancy).
// ---------------------------------------------------------------------------

static constexpr int NPIX = 4096;
typedef long long i64;
typedef __attribute__((ext_vector_type(8))) short s16x8;
typedef __attribute__((ext_vector_type(8))) _Float16 f16x8;
typedef __attribute__((ext_vector_type(4))) float f32x4;

__device__ inline f32x4 MF(s16x8 a, s16x8 b, f32x4 c) {
  return __builtin_amdgcn_mfma_f32_16x16x32_f16(
      __builtin_bit_cast(f16x8, a), __builtin_bit_cast(f16x8, b), c, 0, 0, 0);
}
__device__ inline short f2h(float x) {
  return __builtin_bit_cast(short, (_Float16)x);
}
__device__ inline unsigned pk2(float a, float b) {
  return (unsigned)(unsigned short)f2h(a) | ((unsigned)(unsigned short)f2h(b) << 16);
}

#define LDX 72    // Xs row stride in shorts (64 c + 8 pad, 144B)
#define LDK 136   // kh/vv row stride in shorts (128 px + 8 pad; 17 groups ≡ 1 mod 8)
#define LDQ 72    // qh row stride in shorts (64 + 8 pad, 144B)

// ---------------- K1: depthwise 3x3, pad 1; 4 y/thread; fp16 out -----------
__global__ __launch_bounds__(256) void dwconv_kernel(const float* __restrict__ fmap,
                                                     const float* __restrict__ Wdw,
                                                     short* __restrict__ dwh) {
  i64 p4 = (i64)blockIdx.x * 256 + threadIdx.x;    // over 16*256*64*16
  const int yq = (int)(p4 & 15);
  const int x  = (int)((p4 >> 4) & 63);
  const int c  = (int)((p4 >> 10) & 255);
  const i64 bc = p4 >> 10;
  const float* img = fmap + bc * (i64)NPIX;
  const float* w = Wdw + c * 9;
  const int y0 = yq * 4;
  float a0 = 0.f, a1 = 0.f, a2 = 0.f, a3 = 0.f;
  #pragma unroll
  for (int dx = -1; dx <= 1; ++dx) {
    const int xx = x + dx;
    if ((unsigned)xx < 64u) {
      const float* row = img + xx * 64 + y0;
      const f32x4 v = *(const f32x4*)row;
      const float vm = (y0 > 0)  ? row[-1] : 0.f;
      const float vp = (y0 < 60) ? row[4]  : 0.f;
      const float wm = w[(dx + 1) * 3], wc = w[(dx + 1) * 3 + 1], wp = w[(dx + 1) * 3 + 2];
      a0 = fmaf(wm, vm,   fmaf(wc, v[0], fmaf(wp, v[1], a0)));
      a1 = fmaf(wm, v[0], fmaf(wc, v[1], fmaf(wp, v[2], a1)));
      a2 = fmaf(wm, v[1], fmaf(wc, v[2], fmaf(wp, v[3], a2)));
      a3 = fmaf(wm, v[2], fmaf(wc, v[3], fmaf(wp, vp,   a3)));
    }
  }
  *(uint2*)&dwh[bc * (i64)NPIX + x * 64 + y0] = make_uint2(pk2(a0, a1), pk2(a2, a3));
}

// ---------------- K2: weights -> fp16 --------------------------------------
__global__ __launch_bounds__(256) void wprep_kernel(const float* __restrict__ Wq,
                                                    const float* __restrict__ Wpw,
                                                    const float* __restrict__ Wout,
                                                    short* __restrict__ wh) {
  int i = blockIdx.x * 256 + threadIdx.x;
  float v;
  if (i < 131072) v = Wq[i];
  else if (i < 393216) v = Wpw[i - 131072];
  else v = Wout[i - 393216];
  wh[i] = f2h(v);
}

// ---------------- K3a: transpose+convert fp32 [c][px] -> fp16 [px][c] ------
__global__ __launch_bounds__(256) void tcvt_kernel(const float* __restrict__ src,
                                                   short* __restrict__ dst,
                                                   int src_px0, int nsl) {
  __shared__ short T[64 * 260];
  const int pxt = blockIdx.x * 256, ct = blockIdx.y * 64, b = blockIdx.z;
  const int t = threadIdx.x;
  const int pxq = t & 63, cl = t >> 6;
  const float* sp = src + (i64)(b * 256 + ct) * NPIX + src_px0 + pxt;
  #pragma unroll
  for (int cc = 0; cc < 16; ++cc) {
    const int c = cl + cc * 4;
    f32x4 v = *(const f32x4*)&sp[(i64)c * NPIX + pxq * 4];
    *(uint2*)&T[c * 260 + pxq * 4] = make_uint2(pk2(v[0], v[1]), pk2(v[2], v[3]));
  }
  __syncthreads();
  short arr[64];
  #pragma unroll
  for (int c = 0; c < 64; ++c) arr[c] = T[c * 260 + t];
  short* dp = dst + ((i64)b * nsl + pxt + t) * 256 + ct;
  #pragma unroll
  for (int j = 0; j < 8; ++j)
    *(uint4*)&dp[j * 8] = *(const uint4*)&arr[j * 8];
}

// ---------------- K3b: transpose fp16 [c][px] -> fp16 [px][c] --------------
__global__ __launch_bounds__(256) void tcvt16_kernel(const short* __restrict__ src,
                                                     short* __restrict__ dst) {
  __shared__ short T[64 * 260];
  const int pxt = blockIdx.x * 256, ct = blockIdx.y * 64, b = blockIdx.z;
  const int t = threadIdx.x;
  const int pxq = t & 63, cl = t >> 6;
  const short* sp = src + (i64)(b * 256 + ct) * NPIX + pxt;
  #pragma unroll
  for (int cc = 0; cc < 16; ++cc) {
    const int c = cl + cc * 4;
    *(uint2*)&T[c * 260 + pxq * 4] = *(const uint2*)&sp[(i64)c * NPIX + pxq * 4];
  }
  __syncthreads();
  short arr[64];
  #pragma unroll
  for (int c = 0; c < 64; ++c) arr[c] = T[c * 260 + t];
  short* dp = dst + ((i64)b * NPIX + pxt + t) * 256 + ct;
  #pragma unroll
  for (int j = 0; j < 8; ++j)
    *(uint4*)&dp[j * 8] = *(const uint4*)&arr[j * 8];
}

// ---------------- K4: fused k/v GEMM + exp + ctx partial -------------------
// grid (8 chunks of 512 px, 8 h, 16 b). Double-buffered Xs; 1 barrier/BK.
__global__ __launch_bounds__(256) void ctx_kernel(const short* __restrict__ wh,
                                                  const short* __restrict__ dwT,
                                                  float* __restrict__ ctx_part,
                                                  float* __restrict__ s_part) {
  __shared__ short Xs[2][128 * LDX];
  __shared__ short kh[64 * LDK];
  __shared__ short vv[64 * LDK];
  const int chunk = blockIdx.x, h = blockIdx.y, b = blockIdx.z;
  const int tid = threadIdx.x, lane = tid & 63, w = tid >> 6;
  const int fr = lane & 15, fg = lane >> 4;
  const int wcv = w & 1, wpx = w >> 1;     // wcv: k/v half; wpx: px half
  const int wrow0 = (wcv ? 512 : 0) + h * 64;
  const short* W = wh + 131072 + (i64)wrow0 * 256;
  const short* Xg = dwT + ((i64)b * NPIX + chunk * 512) * 256;

  f32x4 acc2[2][2];
  #pragma unroll
  for (int m = 0; m < 2; ++m)
    #pragma unroll
    for (int n = 0; n < 2; ++n) acc2[m][n] = (f32x4)0.f;
  float srun[4] = {0.f, 0.f, 0.f, 0.f};

  const int r0 = tid >> 3, scq = tid & 7;  // staging: 32 rows x 8 col-groups
  s16x8 sv[4];
  auto cload = [&](int g) {
    const int itg = g >> 2, c0g = (g & 3) * 64;
    #pragma unroll
    for (int j = 0; j < 4; ++j)
      sv[j] = *(const s16x8*)&Xg[(i64)(itg * 128 + r0 + j * 32) * 256 + c0g + scq * 8];
  };
  auto cwrite = [&](int bf) {
    #pragma unroll
    for (int j = 0; j < 4; ++j) {
      const int r = r0 + j * 32;
      *(s16x8*)&Xs[bf][r * LDX + ((scq ^ ((r >> 4) & 7)) * 8)] = sv[j];
    }
  };

  cload(0);
  cwrite(0);
  __syncthreads();

  for (int it = 0; it < 4; ++it) {
    f32x4 acc1[4][4];
    #pragma unroll
    for (int m = 0; m < 4; ++m)
      #pragma unroll
      for (int n = 0; n < 4; ++n) acc1[m][n] = (f32x4)0.f;

    for (int ks = 0; ks < 4; ++ks) {
      const int g = it * 4 + ks;
      if (g < 15) cload(g + 1);           // prefetch (hidden under MFMA)
      const int c0 = (g & 3) * 64;
      const short* Xb = Xs[g & 1];
      #pragma unroll
      for (int k2 = 0; k2 < 2; ++k2) {
        s16x8 a[4], bb[4];
        #pragma unroll
        for (int m = 0; m < 4; ++m) {
          const int px = wpx * 64 + m * 16 + fr;
          a[m] = *(const s16x8*)&Xb[px * LDX + (((k2 * 4 + fg) ^ (wpx * 4 + m)) & 7) * 8];
        }
        #pragma unroll
        for (int n = 0; n < 4; ++n)
          bb[n] = *(const s16x8*)&W[(i64)(n * 16 + fr) * 256 + c0 + k2 * 32 + fg * 8];
        #pragma unroll
        for (int m = 0; m < 4; ++m)
          #pragma unroll
          for (int n = 0; n < 4; ++n)
            acc1[m][n] = MF(a[m], bb[n], acc1[m][n]);
      }
      if (g < 15) cwrite((g + 1) & 1);    // waits vmcnt; other buffer
      __syncthreads();
    }
    // k-half: exp (no max-sub; values bounded), per-channel running sums
    if (wcv == 0) {
      #pragma unroll
      for (int m = 0; m < 4; ++m)
        #pragma unroll
        for (int n = 0; n < 4; ++n)
          #pragma unroll
          for (int r = 0; r < 4; ++r) {
            float e = __expf(acc1[m][n][r]);
            acc1[m][n][r] = e;
            srun[n] += e;
          }
    }
    // packed writes into [ch][px]; NO XOR (LDK stride rotates banks)
    {
      short* dst = wcv ? vv : kh;
      #pragma unroll
      for (int m = 0; m < 4; ++m)
        #pragma unroll
        for (int n = 0; n < 4; ++n) {
          const int ch = n * 16 + fr;
          const int col = (wpx * 8 + m * 2 + (fg >> 1)) * 8 + (fg & 1) * 4;
          *(uint2*)&dst[ch * LDK + col] =
              make_uint2(pk2(acc1[m][n][0], acc1[m][n][1]),
                         pk2(acc1[m][n][2], acc1[m][n][3]));
        }
    }
    __syncthreads();
    // GEMM2: ctx[d][e] += sum_px kh[d][px] * vv[e][px]; NO XOR on reads
    #pragma unroll
    for (int k2 = 0; k2 < 4; ++k2) {
      const int colg = (k2 * 4 + fg) * 8;
      s16x8 a2[2], b2[2];
      #pragma unroll
      for (int m2 = 0; m2 < 2; ++m2)
        a2[m2] = *(const s16x8*)&kh[(wcv * 32 + m2 * 16 + fr) * LDK + colg];
      #pragma unroll
      for (int n2 = 0; n2 < 2; ++n2)
        b2[n2] = *(const s16x8*)&vv[(wpx * 32 + n2 * 16 + fr) * LDK + colg];
      #pragma unroll
      for (int m2 = 0; m2 < 2; ++m2)
        #pragma unroll
        for (int n2 = 0; n2 < 2; ++n2)
          acc2[m2][n2] = MF(a2[m2], b2[n2], acc2[m2][n2]);
    }
    // no bottom barrier: next it's ks barriers separate GEMM2 reads from
    // the next kh/vv writes.
  }
  __syncthreads();   // last GEMM2 reads done before kh reuse as sredp
  // write ctx partial [d][e]
  float* cp = ctx_part + (i64)((b * 8 + h) * 8 + chunk) * 4096;
  #pragma unroll
  for (int m2 = 0; m2 < 2; ++m2)
    #pragma unroll
    for (int n2 = 0; n2 < 2; ++n2)
      #pragma unroll
      for (int r = 0; r < 4; ++r) {
        const int d = wcv * 32 + m2 * 16 + fg * 4 + r;
        const int e = wpx * 32 + n2 * 16 + fr;
        cp[d * 64 + e] = acc2[m2][n2][r];
      }
  // per-channel sumexp: reduce over fg lanes, stash in kh (dead), emit
  float* sredp = (float*)kh;
  if (wcv == 0) {
    #pragma unroll
    for (int n = 0; n < 4; ++n) {
      float s = srun[n];
      s += __shfl_xor(s, 16);
      s += __shfl_xor(s, 32);
      if (fg == 0) sredp[wpx * 64 + n * 16 + fr] = s;
    }
  }
  __syncthreads();
  if (tid < 64)
    s_part[(i64)((b * 8 + h) * 8 + chunk) * 64 + tid] = sredp[tid] + sredp[64 + tid];
}

// ---------------- K5: merge chunk partials -> ctxh fp16 [bh][e][d] ---------
__global__ __launch_bounds__(256) void merge_kernel(const float* __restrict__ part,
                                                    const float* __restrict__ s_part,
                                                    short* __restrict__ ctxh) {
  const int bh = blockIdx.x, t = threadIdx.x;
  const int e = t & 63, db = t >> 6;
  const float* p = part + (i64)bh * 8 * 4096;
  const float* sp = s_part + (i64)bh * 8 * 64;
  #pragma unroll 4
  for (int dd = 0; dd < 16; ++dd) {
    const int d = db * 16 + dd;
    float s = 0.f, c = 0.f;
    #pragma unroll
    for (int k = 0; k < 8; ++k) {
      s += sp[k * 64 + d];
      c += p[k * 4096 + d * 64 + e];
    }
    ctxh[(i64)bh * 4096 + e * 64 + d] = f2h(c / s);
  }
}

// ---------------- K6: fused q GEMM + softmax + PV + GELU -> out2 -----------
// grid (NS/128, 8 h, 16 b). M=64 d x N=128 px, K=256 (BK=64). (unchanged)
__global__ __launch_bounds__(256) void qpv_kernel(const short* __restrict__ wh,
                                                  const short* __restrict__ fmapT,
                                                  const short* __restrict__ ctxh,
                                                  short* __restrict__ out2, int NS) {
  __shared__ short Xs[128 * LDX];
  __shared__ short qh[128 * LDQ];
  __shared__ float sden[2][128];
  const int h = blockIdx.y, b = blockIdx.z;
  const int i0 = blockIdx.x * 128;
  const int tid = threadIdx.x, lane = tid & 63, w = tid >> 6;
  const int fr = lane & 15, fg = lane >> 4;
  const int dh = w & 1, ih = w >> 1;
  const short* W = wh + (i64)(h * 64 + dh * 32) * 256;
  const short* Xg = fmapT + ((i64)b * NS + i0) * 256;

  f32x4 acc[2][4];
  #pragma unroll
  for (int m = 0; m < 2; ++m)
    #pragma unroll
    for (int n = 0; n < 4; ++n) acc[m][n] = (f32x4)0.f;

  const int r0 = tid >> 3, scq = tid & 7;

  for (int ks = 0; ks < 4; ++ks) {         // BK = 64
    const int c0 = ks * 64;
    s16x8 sv[4];
    #pragma unroll
    for (int j = 0; j < 4; ++j)
      sv[j] = *(const s16x8*)&Xg[(i64)(r0 + j * 32) * 256 + c0 + scq * 8];
    __syncthreads();
    #pragma unroll
    for (int j = 0; j < 4; ++j) {
      const int r = r0 + j * 32;
      *(s16x8*)&Xs[r * LDX + ((scq ^ ((r >> 4) & 7)) * 8)] = sv[j];
    }
    __syncthreads();
    #pragma unroll
    for (int k2 = 0; k2 < 2; ++k2) {
      s16x8 a[2], bfr[4];
      #pragma unroll
      for (int m = 0; m < 2; ++m)
        a[m] = *(const s16x8*)&W[(i64)(m * 16 + fr) * 256 + c0 + k2 * 32 + fg * 8];
      #pragma unroll
      for (int n = 0; n < 4; ++n) {
        const int px = ih * 64 + n * 16 + fr;
        bfr[n] = *(const s16x8*)&Xs[px * LDX + (((k2 * 4 + fg) ^ (ih * 4 + n)) & 7) * 8];
      }
      #pragma unroll
      for (int m = 0; m < 2; ++m)
        #pragma unroll
        for (int n = 0; n < 4; ++n)
          acc[m][n] = MF(a[m], bfr[n], acc[m][n]);
    }
  }
  // exp + per-pixel denominator across d (2 waves x 32 d)
  #pragma unroll
  for (int n = 0; n < 4; ++n) {
    float s = 0.f;
    #pragma unroll
    for (int m = 0; m < 2; ++m)
      #pragma unroll
      for (int r = 0; r < 4; ++r) {
        float e = __expf(acc[m][n][r]);
        acc[m][n][r] = e;
        s += e;
      }
    s += __shfl_xor(s, 16);
    s += __shfl_xor(s, 32);
    if (fg == 0) sden[dh][ih * 64 + n * 16 + fr] = s;
  }
  __syncthreads();
  if (tid < 128) sden[0][tid] += sden[1][tid];
  __syncthreads();
  // qhat -> LDS [px][d] fp16 (uint2-packed 4-d chunks)
  #pragma unroll
  for (int n = 0; n < 4; ++n) {
    const int il = ih * 64 + n * 16 + fr;
    const float rs = 0.125f / sden[0][il];
    #pragma unroll
    for (int m = 0; m < 2; ++m) {
      const int d0 = dh * 32 + m * 16 + fg * 4;
      *(uint2*)&qh[il * LDQ + d0] =
          make_uint2(pk2(acc[m][n][0] * rs, acc[m][n][1] * rs),
                     pk2(acc[m][n][2] * rs, acc[m][n][3] * rs));
    }
  }
  __syncthreads();
  // PV: out2[e][px] = sum_d ctx[e][d] * qhat[px][d]
  f32x4 acc3[2][4];
  #pragma unroll
  for (int m = 0; m < 2; ++m)
    #pragma unroll
    for (int n = 0; n < 4; ++n) acc3[m][n] = (f32x4)0.f;
  const i64 cbase = (i64)(b * 8 + h) * 4096;
  #pragma unroll
  for (int k2 = 0; k2 < 2; ++k2) {
    s16x8 a2[2], b2[4];
    #pragma unroll
    for (int m2 = 0; m2 < 2; ++m2)
      a2[m2] = *(const s16x8*)&ctxh[cbase + (i64)(dh * 32 + m2 * 16 + fr) * 64 + k2 * 32 + fg * 8];
    #pragma unroll
    for (int n2 = 0; n2 < 4; ++n2)
      b2[n2] = *(const s16x8*)&qh[(ih * 64 + n2 * 16 + fr) * LDQ + k2 * 32 + fg * 8];
    #pragma unroll
    for (int m2 = 0; m2 < 2; ++m2)
      #pragma unroll
      for (int n2 = 0; n2 < 4; ++n2)
        acc3[m2][n2] = MF(a2[m2], b2[n2], acc3[m2][n2]);
  }
  __syncthreads();   // qh reads done; reuse as transpose buffer
  // GELU + fp16, into qh as [px][e]
  #pragma unroll
  for (int m2 = 0; m2 < 2; ++m2)
    #pragma unroll
    for (int n2 = 0; n2 < 4; ++n2) {
      const int px = ih * 64 + n2 * 16 + fr;
      const int e0 = dh * 32 + m2 * 16 + fg * 4;
      float g[4];
      #pragma unroll
      for (int r = 0; r < 4; ++r) {
        float v = acc3[m2][n2][r];
        g[r] = 0.5f * v * (1.0f + erff(v * 0.70710678118654752f));
      }
      *(uint2*)&qh[px * LDQ + e0] = make_uint2(pk2(g[0], g[1]), pk2(g[2], g[3]));
    }
  __syncthreads();
  // coalesced out2 store: [b][px][512ch]
  {
    const int px = tid >> 1, half = tid & 1;
    short* op = out2 + ((i64)b * NS + i0 + px) * 512 + h * 64 + half * 32;
    #pragma unroll
    for (int j = 0; j < 4; ++j)
      *(uint4*)&op[j * 8] = *(const uint4*)&qh[px * LDQ + half * 32 + j * 8];
  }
}

// ---------------- K7: out = Wout @ gelu-out2 + bout ------------------------
// grid (NS/128, 4 og, 16 b). M=64 o x N=128 px, K=512. Double-buffered Xs.
__global__ __launch_bounds__(256) void wout_kernel(const short* __restrict__ wh,
                                                   const short* __restrict__ out2,
                                                   const float* __restrict__ bout,
                                                   float* __restrict__ Y,
                                                   int pxbase, int NS) {
  __shared__ short Xs[2][128 * LDX];
  const int og = blockIdx.y, b = blockIdx.z;
  const int i0 = blockIdx.x * 128;
  const int tid = threadIdx.x, lane = tid & 63, w = tid >> 6;
  const int fr = lane & 15, fg = lane >> 4;
  const int oh = w & 1, ih = w >> 1;
  const short* W = wh + 393216 + (i64)(og * 64 + oh * 32) * 512;
  const short* Xg = out2 + ((i64)b * NS + i0) * 512;

  f32x4 acc[2][4];
  #pragma unroll
  for (int m = 0; m < 2; ++m)
    #pragma unroll
    for (int n = 0; n < 4; ++n) acc[m][n] = (f32x4)0.f;

  const int r0 = tid >> 3, scq = tid & 7;
  s16x8 sv[4];
  auto wload = [&](int g) {
    #pragma unroll
    for (int j = 0; j < 4; ++j)
      sv[j] = *(const s16x8*)&Xg[(i64)(r0 + j * 32) * 512 + g * 64 + scq * 8];
  };
  auto wwrite = [&](int bf) {
    #pragma unroll
    for (int j = 0; j < 4; ++j) {
      const int r = r0 + j * 32;
      *(s16x8*)&Xs[bf][r * LDX + ((scq ^ ((r >> 4) & 7)) * 8)] = sv[j];
    }
  };

  wload(0);
  wwrite(0);
  __syncthreads();

  for (int ks = 0; ks < 8; ++ks) {         // BK = 64, K = 512
    if (ks < 7) wload(ks + 1);
    const int c0 = ks * 64;
    const short* Xb = Xs[ks & 1];
    #pragma unroll
    for (int k2 = 0; k2 < 2; ++k2) {
      s16x8 a[2], bfr[4];
      #pragma unroll
      for (int m = 0; m < 2; ++m)
        a[m] = *(const s16x8*)&W[(i64)(m * 16 + fr) * 512 + c0 + k2 * 32 + fg * 8];
      #pragma unroll
      for (int n = 0; n < 4; ++n) {
        const int px = ih * 64 + n * 16 + fr;
        bfr[n] = *(const s16x8*)&Xb[px * LDX + (((k2 * 4 + fg) ^ (ih * 4 + n)) & 7) * 8];
      }
      #pragma unroll
      for (int m = 0; m < 2; ++m)
        #pragma unroll
        for (int n = 0; n < 4; ++n)
          acc[m][n] = MF(a[m], bfr[n], acc[m][n]);
    }
    if (ks < 7) wwrite((ks + 1) & 1);
    __syncthreads();
  }
  #pragma unroll
  for (int m = 0; m < 2; ++m)
    #pragma unroll
    for (int r = 0; r < 4; ++r) {
      const int o = og * 64 + oh * 32 + m * 16 + fg * 4 + r;
      const float bv = bout[o];
      #pragma unroll
      for (int n = 0; n < 4; ++n)
        Y[(i64)(b * 256 + o) * NPIX + pxbase + i0 + ih * 64 + n * 16 + fr] =
            acc[m][n][r] + bv;
    }
}

// ---------------------------------------------------------------------------
extern "C" void kernel_launch(void* const* d_in, const int* in_sizes, int n_in,
                              void* d_out, int out_size, void* d_ws, size_t ws_size,
                              hipStream_t stream) {
  const float* fmap = (const float*)d_in[0];
  const float* Wq   = (const float*)d_in[1];
  const float* Wdw  = (const float*)d_in[2];
  const float* Wpw  = (const float*)d_in[3];
  const float* Wout = (const float*)d_in[4];
  const float* bout = (const float*)d_in[5];
  float* out = (float*)d_out;
  short* dwh = (short*)d_out;   // d_out hosts dw fp16 (32MB; dead before wout)

  // ws layout (bytes), phase-aliased big region:
  //   wh       [0,       1048576)
  //   s_part   [1048576, 1572864)
  //   ctxh     [1572864, 2621440)
  //   BIG      [2621440, ...):
  //     phase1: ctx_part [2621440, 19398656)  (16.8 MB)
  //             dwT      [19398656, 52953088) (33.5 MB)
  //     phase2: fmapT    [2621440, +33.5MB/S)
  //             out2     [..,      +67MB/S)
  char* ws = (char*)d_ws;
  short* wh       = (short*)(ws);
  float* s_part   = (float*)(ws + 1048576);
  short* ctxh     = (short*)(ws + 1572864);
  float* ctx_part = (float*)(ws + 2621440);
  short* dwT      = (short*)(ws + 19398656);

  i64 avail = (i64)ws_size - 2621440;
  const int S = (avail >= 100663296) ? 1 : 2;
  const int NS = NPIX / S;
  short* fmapT = (short*)(ws + 2621440);
  short* out2  = fmapT + (i64)16 * NS * 256;

  dwconv_kernel<<<16384, 256, 0, stream>>>(fmap, Wdw, dwh);
  wprep_kernel<<<2048, 256, 0, stream>>>(Wq, Wpw, Wout, wh);
  tcvt16_kernel<<<dim3(16, 4, 16), 256, 0, stream>>>(dwh, dwT);
  ctx_kernel<<<dim3(8, 8, 16), 256, 0, stream>>>(wh, dwT, ctx_part, s_part);
  merge_kernel<<<128, 256, 0, stream>>>(ctx_part, s_part, ctxh);
  for (int s = 0; s < S; ++s) {
    tcvt_kernel<<<dim3(NS / 256, 4, 16), 256, 0, stream>>>(fmap, fmapT, s * NS, NS);
    qpv_kernel<<<dim3(NS / 128, 8, 16), 256, 0, stream>>>(wh, fmapT, ctxh, out2, NS);
    wout_kernel<<<dim3(NS / 128, 4, 16), 256, 0, stream>>>(wh, out2, bout, out, s * NS, NS);
  }
}

// Round 9
// 279.496 us; speedup vs baseline: 5.6403x; 1.0783x over previous
//
#include <hip/hip_runtime.h>
#include <math.h>

// ---------------------------------------------------------------------------
// LinearAttention: B=16, DIM=256, H=W=64 (n=4096), HEADS=8, DH=64, INNER=512
// Round 9: kill global-load latency on ctx/wout critical path.
//   - ctx: W fragments register-double-buffered (prefetch next window's 8
//     W loads alongside X prefetch; MFMA window = regs + ds_reads only).
//   - ctx chunks 8 -> 4 (512 blocks = exactly 2/CU, halved partial traffic).
//   - wout: same W register prefetch (4 fragments/window).
// ---------------------------------------------------------------------------

static constexpr int NPIX = 4096;
typedef long long i64;
typedef __attribute__((ext_vector_type(8))) short s16x8;
typedef __attribute__((ext_vector_type(8))) _Float16 f16x8;
typedef __attribute__((ext_vector_type(4))) float f32x4;

__device__ inline f32x4 MF(s16x8 a, s16x8 b, f32x4 c) {
  return __builtin_amdgcn_mfma_f32_16x16x32_f16(
      __builtin_bit_cast(f16x8, a), __builtin_bit_cast(f16x8, b), c, 0, 0, 0);
}
__device__ inline short f2h(float x) {
  return __builtin_bit_cast(short, (_Float16)x);
}
__device__ inline unsigned pk2(float a, float b) {
  return (unsigned)(unsigned short)f2h(a) | ((unsigned)(unsigned short)f2h(b) << 16);
}

#define LDX 72    // Xs row stride in shorts (64 c + 8 pad, 144B)
#define LDK 136   // kh/vv row stride in shorts (128 px + 8 pad; 17 groups ≡ 1 mod 8)
#define LDQ 72    // qh row stride in shorts (64 + 8 pad, 144B)

// ---------------- K1: depthwise 3x3, pad 1; 4 y/thread; fp16 out -----------
__global__ __launch_bounds__(256) void dwconv_kernel(const float* __restrict__ fmap,
                                                     const float* __restrict__ Wdw,
                                                     short* __restrict__ dwh) {
  i64 p4 = (i64)blockIdx.x * 256 + threadIdx.x;    // over 16*256*64*16
  const int yq = (int)(p4 & 15);
  const int x  = (int)((p4 >> 4) & 63);
  const int c  = (int)((p4 >> 10) & 255);
  const i64 bc = p4 >> 10;
  const float* img = fmap + bc * (i64)NPIX;
  const float* w = Wdw + c * 9;
  const int y0 = yq * 4;
  float a0 = 0.f, a1 = 0.f, a2 = 0.f, a3 = 0.f;
  #pragma unroll
  for (int dx = -1; dx <= 1; ++dx) {
    const int xx = x + dx;
    if ((unsigned)xx < 64u) {
      const float* row = img + xx * 64 + y0;
      const f32x4 v = *(const f32x4*)row;
      const float vm = (y0 > 0)  ? row[-1] : 0.f;
      const float vp = (y0 < 60) ? row[4]  : 0.f;
      const float wm = w[(dx + 1) * 3], wc = w[(dx + 1) * 3 + 1], wp = w[(dx + 1) * 3 + 2];
      a0 = fmaf(wm, vm,   fmaf(wc, v[0], fmaf(wp, v[1], a0)));
      a1 = fmaf(wm, v[0], fmaf(wc, v[1], fmaf(wp, v[2], a1)));
      a2 = fmaf(wm, v[1], fmaf(wc, v[2], fmaf(wp, v[3], a2)));
      a3 = fmaf(wm, v[2], fmaf(wc, v[3], fmaf(wp, vp,   a3)));
    }
  }
  *(uint2*)&dwh[bc * (i64)NPIX + x * 64 + y0] = make_uint2(pk2(a0, a1), pk2(a2, a3));
}

// ---------------- K2: weights -> fp16 --------------------------------------
__global__ __launch_bounds__(256) void wprep_kernel(const float* __restrict__ Wq,
                                                    const float* __restrict__ Wpw,
                                                    const float* __restrict__ Wout,
                                                    short* __restrict__ wh) {
  int i = blockIdx.x * 256 + threadIdx.x;
  float v;
  if (i < 131072) v = Wq[i];
  else if (i < 393216) v = Wpw[i - 131072];
  else v = Wout[i - 393216];
  wh[i] = f2h(v);
}

// ---------------- K3a: transpose+convert fp32 [c][px] -> fp16 [px][c] ------
__global__ __launch_bounds__(256) void tcvt_kernel(const float* __restrict__ src,
                                                   short* __restrict__ dst,
                                                   int src_px0, int nsl) {
  __shared__ short T[64 * 260];
  const int pxt = blockIdx.x * 256, ct = blockIdx.y * 64, b = blockIdx.z;
  const int t = threadIdx.x;
  const int pxq = t & 63, cl = t >> 6;
  const float* sp = src + (i64)(b * 256 + ct) * NPIX + src_px0 + pxt;
  #pragma unroll
  for (int cc = 0; cc < 16; ++cc) {
    const int c = cl + cc * 4;
    f32x4 v = *(const f32x4*)&sp[(i64)c * NPIX + pxq * 4];
    *(uint2*)&T[c * 260 + pxq * 4] = make_uint2(pk2(v[0], v[1]), pk2(v[2], v[3]));
  }
  __syncthreads();
  short arr[64];
  #pragma unroll
  for (int c = 0; c < 64; ++c) arr[c] = T[c * 260 + t];
  short* dp = dst + ((i64)b * nsl + pxt + t) * 256 + ct;
  #pragma unroll
  for (int j = 0; j < 8; ++j)
    *(uint4*)&dp[j * 8] = *(const uint4*)&arr[j * 8];
}

// ---------------- K3b: transpose fp16 [c][px] -> fp16 [px][c] --------------
__global__ __launch_bounds__(256) void tcvt16_kernel(const short* __restrict__ src,
                                                     short* __restrict__ dst) {
  __shared__ short T[64 * 260];
  const int pxt = blockIdx.x * 256, ct = blockIdx.y * 64, b = blockIdx.z;
  const int t = threadIdx.x;
  const int pxq = t & 63, cl = t >> 6;
  const short* sp = src + (i64)(b * 256 + ct) * NPIX + pxt;
  #pragma unroll
  for (int cc = 0; cc < 16; ++cc) {
    const int c = cl + cc * 4;
    *(uint2*)&T[c * 260 + pxq * 4] = *(const uint2*)&sp[(i64)c * NPIX + pxq * 4];
  }
  __syncthreads();
  short arr[64];
  #pragma unroll
  for (int c = 0; c < 64; ++c) arr[c] = T[c * 260 + t];
  short* dp = dst + ((i64)b * NPIX + pxt + t) * 256 + ct;
  #pragma unroll
  for (int j = 0; j < 8; ++j)
    *(uint4*)&dp[j * 8] = *(const uint4*)&arr[j * 8];
}

// ---------------- K4: fused k/v GEMM + exp + ctx partial -------------------
// grid (4 chunks of 1024 px, 8 h, 16 b). Xs double-buffered; W fragments
// register-double-buffered (prefetched one window ahead). 1 barrier/window.
__global__ __launch_bounds__(256) void ctx_kernel(const short* __restrict__ wh,
                                                  const short* __restrict__ dwT,
                                                  float* __restrict__ ctx_part,
                                                  float* __restrict__ s_part) {
  __shared__ short Xs[2][128 * LDX];
  __shared__ short kh[64 * LDK];
  __shared__ short vv[64 * LDK];
  const int chunk = blockIdx.x, h = blockIdx.y, b = blockIdx.z;
  const int tid = threadIdx.x, lane = tid & 63, w = tid >> 6;
  const int fr = lane & 15, fg = lane >> 4;
  const int wcv = w & 1, wpx = w >> 1;     // wcv: k/v half; wpx: px half
  const int wrow0 = (wcv ? 512 : 0) + h * 64;
  const short* W = wh + 131072 + (i64)wrow0 * 256;
  const short* Xg = dwT + ((i64)b * NPIX + chunk * 1024) * 256;

  f32x4 acc2[2][2];
  #pragma unroll
  for (int m = 0; m < 2; ++m)
    #pragma unroll
    for (int n = 0; n < 2; ++n) acc2[m][n] = (f32x4)0.f;
  float srun[4] = {0.f, 0.f, 0.f, 0.f};

  const int r0 = tid >> 3, scq = tid & 7;  // staging: 32 rows x 8 col-groups
  s16x8 sv[4];
  s16x8 Wr[2][2][4];                       // [buf][k2][n]
  auto cload = [&](int g) {
    const int itg = g >> 2, c0g = (g & 3) * 64;
    #pragma unroll
    for (int j = 0; j < 4; ++j)
      sv[j] = *(const s16x8*)&Xg[(i64)(itg * 128 + r0 + j * 32) * 256 + c0g + scq * 8];
  };
  auto cwrite = [&](int bf) {
    #pragma unroll
    for (int j = 0; j < 4; ++j) {
      const int r = r0 + j * 32;
      *(s16x8*)&Xs[bf][r * LDX + ((scq ^ ((r >> 4) & 7)) * 8)] = sv[j];
    }
  };
  auto wload = [&](int g, int bf) {
    const int c0g = (g & 3) * 64;
    #pragma unroll
    for (int k2 = 0; k2 < 2; ++k2)
      #pragma unroll
      for (int n = 0; n < 4; ++n)
        Wr[bf][k2][n] = *(const s16x8*)&W[(i64)(n * 16 + fr) * 256 + c0g + k2 * 32 + fg * 8];
  };

  cload(0);
  wload(0, 0);
  cwrite(0);
  __syncthreads();

  for (int it = 0; it < 8; ++it) {
    f32x4 acc1[4][4];
    #pragma unroll
    for (int m = 0; m < 4; ++m)
      #pragma unroll
      for (int n = 0; n < 4; ++n) acc1[m][n] = (f32x4)0.f;

    #pragma unroll
    for (int ks = 0; ks < 4; ++ks) {
      const int g = it * 4 + ks;           // g&1 == ks&1 (it*4 even)
      if (g < 31) {
        cload(g + 1);                      // prefetch X (hidden under MFMA)
        wload(g + 1, (ks + 1) & 1);        // prefetch W into other reg buffer
      }
      const short* Xb = Xs[ks & 1];
      #pragma unroll
      for (int k2 = 0; k2 < 2; ++k2) {
        s16x8 a[4];
        #pragma unroll
        for (int m = 0; m < 4; ++m) {
          const int px = wpx * 64 + m * 16 + fr;
          a[m] = *(const s16x8*)&Xb[px * LDX + (((k2 * 4 + fg) ^ (wpx * 4 + m)) & 7) * 8];
        }
        #pragma unroll
        for (int m = 0; m < 4; ++m)
          #pragma unroll
          for (int n = 0; n < 4; ++n)
            acc1[m][n] = MF(a[m], Wr[ks & 1][k2][n], acc1[m][n]);
      }
      if (g < 31) cwrite((ks + 1) & 1);    // waits vmcnt; other buffer
      __syncthreads();
    }
    // k-half: exp (no max-sub; values bounded), per-channel running sums
    if (wcv == 0) {
      #pragma unroll
      for (int m = 0; m < 4; ++m)
        #pragma unroll
        for (int n = 0; n < 4; ++n)
          #pragma unroll
          for (int r = 0; r < 4; ++r) {
            float e = __expf(acc1[m][n][r]);
            acc1[m][n][r] = e;
            srun[n] += e;
          }
    }
    // packed writes into [ch][px]; NO XOR (LDK stride rotates banks)
    {
      short* dst = wcv ? vv : kh;
      #pragma unroll
      for (int m = 0; m < 4; ++m)
        #pragma unroll
        for (int n = 0; n < 4; ++n) {
          const int ch = n * 16 + fr;
          const int col = (wpx * 8 + m * 2 + (fg >> 1)) * 8 + (fg & 1) * 4;
          *(uint2*)&dst[ch * LDK + col] =
              make_uint2(pk2(acc1[m][n][0], acc1[m][n][1]),
                         pk2(acc1[m][n][2], acc1[m][n][3]));
        }
    }
    __syncthreads();
    // GEMM2: ctx[d][e] += sum_px kh[d][px] * vv[e][px]
    #pragma unroll
    for (int k2 = 0; k2 < 4; ++k2) {
      const int colg = (k2 * 4 + fg) * 8;
      s16x8 a2[2], b2[2];
      #pragma unroll
      for (int m2 = 0; m2 < 2; ++m2)
        a2[m2] = *(const s16x8*)&kh[(wcv * 32 + m2 * 16 + fr) * LDK + colg];
      #pragma unroll
      for (int n2 = 0; n2 < 2; ++n2)
        b2[n2] = *(const s16x8*)&vv[(wpx * 32 + n2 * 16 + fr) * LDK + colg];
      #pragma unroll
      for (int m2 = 0; m2 < 2; ++m2)
        #pragma unroll
        for (int n2 = 0; n2 < 2; ++n2)
          acc2[m2][n2] = MF(a2[m2], b2[n2], acc2[m2][n2]);
    }
    // no bottom barrier: next it's ks barriers separate GEMM2 reads from
    // the next kh/vv writes.
  }
  __syncthreads();   // last GEMM2 reads done before kh reuse as sredp
  // write ctx partial [d][e]
  float* cp = ctx_part + (i64)((b * 8 + h) * 4 + chunk) * 4096;
  #pragma unroll
  for (int m2 = 0; m2 < 2; ++m2)
    #pragma unroll
    for (int n2 = 0; n2 < 2; ++n2)
      #pragma unroll
      for (int r = 0; r < 4; ++r) {
        const int d = wcv * 32 + m2 * 16 + fg * 4 + r;
        const int e = wpx * 32 + n2 * 16 + fr;
        cp[d * 64 + e] = acc2[m2][n2][r];
      }
  // per-channel sumexp: reduce over fg lanes, stash in kh (dead), emit
  float* sredp = (float*)kh;
  if (wcv == 0) {
    #pragma unroll
    for (int n = 0; n < 4; ++n) {
      float s = srun[n];
      s += __shfl_xor(s, 16);
      s += __shfl_xor(s, 32);
      if (fg == 0) sredp[wpx * 64 + n * 16 + fr] = s;
    }
  }
  __syncthreads();
  if (tid < 64)
    s_part[(i64)((b * 8 + h) * 4 + chunk) * 64 + tid] = sredp[tid] + sredp[64 + tid];
}

// ---------------- K5: merge chunk partials -> ctxh fp16 [bh][e][d] ---------
__global__ __launch_bounds__(256) void merge_kernel(const float* __restrict__ part,
                                                    const float* __restrict__ s_part,
                                                    short* __restrict__ ctxh) {
  const int bh = blockIdx.x, t = threadIdx.x;
  const int e = t & 63, db = t >> 6;
  const float* p = part + (i64)bh * 4 * 4096;
  const float* sp = s_part + (i64)bh * 4 * 64;
  #pragma unroll 4
  for (int dd = 0; dd < 16; ++dd) {
    const int d = db * 16 + dd;
    float s = 0.f, c = 0.f;
    #pragma unroll
    for (int k = 0; k < 4; ++k) {
      s += sp[k * 64 + d];
      c += p[k * 4096 + d * 64 + e];
    }
    ctxh[(i64)bh * 4096 + e * 64 + d] = f2h(c / s);
  }
}

// ---------------- K6: fused q GEMM + softmax + PV + GELU -> out2 -----------
// grid (NS/128, 8 h, 16 b). M=64 d x N=128 px, K=256 (BK=64). (unchanged)
__global__ __launch_bounds__(256) void qpv_kernel(const short* __restrict__ wh,
                                                  const short* __restrict__ fmapT,
                                                  const short* __restrict__ ctxh,
                                                  short* __restrict__ out2, int NS) {
  __shared__ short Xs[128 * LDX];
  __shared__ short qh[128 * LDQ];
  __shared__ float sden[2][128];
  const int h = blockIdx.y, b = blockIdx.z;
  const int i0 = blockIdx.x * 128;
  const int tid = threadIdx.x, lane = tid & 63, w = tid >> 6;
  const int fr = lane & 15, fg = lane >> 4;
  const int dh = w & 1, ih = w >> 1;
  const short* W = wh + (i64)(h * 64 + dh * 32) * 256;
  const short* Xg = fmapT + ((i64)b * NS + i0) * 256;

  f32x4 acc[2][4];
  #pragma unroll
  for (int m = 0; m < 2; ++m)
    #pragma unroll
    for (int n = 0; n < 4; ++n) acc[m][n] = (f32x4)0.f;

  const int r0 = tid >> 3, scq = tid & 7;

  for (int ks = 0; ks < 4; ++ks) {         // BK = 64
    const int c0 = ks * 64;
    s16x8 sv[4];
    #pragma unroll
    for (int j = 0; j < 4; ++j)
      sv[j] = *(const s16x8*)&Xg[(i64)(r0 + j * 32) * 256 + c0 + scq * 8];
    __syncthreads();
    #pragma unroll
    for (int j = 0; j < 4; ++j) {
      const int r = r0 + j * 32;
      *(s16x8*)&Xs[r * LDX + ((scq ^ ((r >> 4) & 7)) * 8)] = sv[j];
    }
    __syncthreads();
    #pragma unroll
    for (int k2 = 0; k2 < 2; ++k2) {
      s16x8 a[2], bfr[4];
      #pragma unroll
      for (int m = 0; m < 2; ++m)
        a[m] = *(const s16x8*)&W[(i64)(m * 16 + fr) * 256 + c0 + k2 * 32 + fg * 8];
      #pragma unroll
      for (int n = 0; n < 4; ++n) {
        const int px = ih * 64 + n * 16 + fr;
        bfr[n] = *(const s16x8*)&Xs[px * LDX + (((k2 * 4 + fg) ^ (ih * 4 + n)) & 7) * 8];
      }
      #pragma unroll
      for (int m = 0; m < 2; ++m)
        #pragma unroll
        for (int n = 0; n < 4; ++n)
          acc[m][n] = MF(a[m], bfr[n], acc[m][n]);
    }
  }
  // exp + per-pixel denominator across d (2 waves x 32 d)
  #pragma unroll
  for (int n = 0; n < 4; ++n) {
    float s = 0.f;
    #pragma unroll
    for (int m = 0; m < 2; ++m)
      #pragma unroll
      for (int r = 0; r < 4; ++r) {
        float e = __expf(acc[m][n][r]);
        acc[m][n][r] = e;
        s += e;
      }
    s += __shfl_xor(s, 16);
    s += __shfl_xor(s, 32);
    if (fg == 0) sden[dh][ih * 64 + n * 16 + fr] = s;
  }
  __syncthreads();
  if (tid < 128) sden[0][tid] += sden[1][tid];
  __syncthreads();
  // qhat -> LDS [px][d] fp16 (uint2-packed 4-d chunks)
  #pragma unroll
  for (int n = 0; n < 4; ++n) {
    const int il = ih * 64 + n * 16 + fr;
    const float rs = 0.125f / sden[0][il];
    #pragma unroll
    for (int m = 0; m < 2; ++m) {
      const int d0 = dh * 32 + m * 16 + fg * 4;
      *(uint2*)&qh[il * LDQ + d0] =
          make_uint2(pk2(acc[m][n][0] * rs, acc[m][n][1] * rs),
                     pk2(acc[m][n][2] * rs, acc[m][n][3] * rs));
    }
  }
  __syncthreads();
  // PV: out2[e][px] = sum_d ctx[e][d] * qhat[px][d]
  f32x4 acc3[2][4];
  #pragma unroll
  for (int m = 0; m < 2; ++m)
    #pragma unroll
    for (int n = 0; n < 4; ++n) acc3[m][n] = (f32x4)0.f;
  const i64 cbase = (i64)(b * 8 + h) * 4096;
  #pragma unroll
  for (int k2 = 0; k2 < 2; ++k2) {
    s16x8 a2[2], b2[4];
    #pragma unroll
    for (int m2 = 0; m2 < 2; ++m2)
      a2[m2] = *(const s16x8*)&ctxh[cbase + (i64)(dh * 32 + m2 * 16 + fr) * 64 + k2 * 32 + fg * 8];
    #pragma unroll
    for (int n2 = 0; n2 < 4; ++n2)
      b2[n2] = *(const s16x8*)&qh[(ih * 64 + n2 * 16 + fr) * LDQ + k2 * 32 + fg * 8];
    #pragma unroll
    for (int m2 = 0; m2 < 2; ++m2)
      #pragma unroll
      for (int n2 = 0; n2 < 4; ++n2)
        acc3[m2][n2] = MF(a2[m2], b2[n2], acc3[m2][n2]);
  }
  __syncthreads();   // qh reads done; reuse as transpose buffer
  // GELU + fp16, into qh as [px][e]
  #pragma unroll
  for (int m2 = 0; m2 < 2; ++m2)
    #pragma unroll
    for (int n2 = 0; n2 < 4; ++n2) {
      const int px = ih * 64 + n2 * 16 + fr;
      const int e0 = dh * 32 + m2 * 16 + fg * 4;
      float g[4];
      #pragma unroll
      for (int r = 0; r < 4; ++r) {
        float v = acc3[m2][n2][r];
        g[r] = 0.5f * v * (1.0f + erff(v * 0.70710678118654752f));
      }
      *(uint2*)&qh[px * LDQ + e0] = make_uint2(pk2(g[0], g[1]), pk2(g[2], g[3]));
    }
  __syncthreads();
  // coalesced out2 store: [b][px][512ch]
  {
    const int px = tid >> 1, half = tid & 1;
    short* op = out2 + ((i64)b * NS + i0 + px) * 512 + h * 64 + half * 32;
    #pragma unroll
    for (int j = 0; j < 4; ++j)
      *(uint4*)&op[j * 8] = *(const uint4*)&qh[px * LDQ + half * 32 + j * 8];
  }
}

// ---------------- K7: out = Wout @ gelu-out2 + bout ------------------------
// grid (NS/128, 4 og, 16 b). M=64 o x N=128 px, K=512. Xs dbuf + W reg dbuf.
__global__ __launch_bounds__(256) void wout_kernel(const short* __restrict__ wh,
                                                   const short* __restrict__ out2,
                                                   const float* __restrict__ bout,
                                                   float* __restrict__ Y,
                                                   int pxbase, int NS) {
  __shared__ short Xs[2][128 * LDX];
  const int og = blockIdx.y, b = blockIdx.z;
  const int i0 = blockIdx.x * 128;
  const int tid = threadIdx.x, lane = tid & 63, w = tid >> 6;
  const int fr = lane & 15, fg = lane >> 4;
  const int oh = w & 1, ih = w >> 1;
  const short* W = wh + 393216 + (i64)(og * 64 + oh * 32) * 512;
  const short* Xg = out2 + ((i64)b * NS + i0) * 512;

  f32x4 acc[2][4];
  #pragma unroll
  for (int m = 0; m < 2; ++m)
    #pragma unroll
    for (int n = 0; n < 4; ++n) acc[m][n] = (f32x4)0.f;

  const int r0 = tid >> 3, scq = tid & 7;
  s16x8 sv[4];
  s16x8 Wr[2][2][2];                       // [buf][k2][m]
  auto wload = [&](int g) {
    #pragma unroll
    for (int j = 0; j < 4; ++j)
      sv[j] = *(const s16x8*)&Xg[(i64)(r0 + j * 32) * 512 + g * 64 + scq * 8];
  };
  auto wwrite = [&](int bf) {
    #pragma unroll
    for (int j = 0; j < 4; ++j) {
      const int r = r0 + j * 32;
      *(s16x8*)&Xs[bf][r * LDX + ((scq ^ ((r >> 4) & 7)) * 8)] = sv[j];
    }
  };
  auto wwload = [&](int g, int bf) {
    #pragma unroll
    for (int k2 = 0; k2 < 2; ++k2)
      #pragma unroll
      for (int m = 0; m < 2; ++m)
        Wr[bf][k2][m] = *(const s16x8*)&W[(i64)(m * 16 + fr) * 512 + g * 64 + k2 * 32 + fg * 8];
  };

  wload(0);
  wwload(0, 0);
  wwrite(0);
  __syncthreads();

  #pragma unroll
  for (int ks = 0; ks < 8; ++ks) {         // BK = 64, K = 512
    if (ks < 7) {
      wload(ks + 1);
      wwload(ks + 1, (ks + 1) & 1);
    }
    const short* Xb = Xs[ks & 1];
    #pragma unroll
    for (int k2 = 0; k2 < 2; ++k2) {
      s16x8 bfr[4];
      #pragma unroll
      for (int n = 0; n < 4; ++n) {
        const int px = ih * 64 + n * 16 + fr;
        bfr[n] = *(const s16x8*)&Xb[px * LDX + (((k2 * 4 + fg) ^ (ih * 4 + n)) & 7) * 8];
      }
      #pragma unroll
      for (int m = 0; m < 2; ++m)
        #pragma unroll
        for (int n = 0; n < 4; ++n)
          acc[m][n] = MF(Wr[ks & 1][k2][m], bfr[n], acc[m][n]);
    }
    if (ks < 7) wwrite((ks + 1) & 1);
    __syncthreads();
  }
  #pragma unroll
  for (int m = 0; m < 2; ++m)
    #pragma unroll
    for (int r = 0; r < 4; ++r) {
      const int o = og * 64 + oh * 32 + m * 16 + fg * 4 + r;
      const float bv = bout[o];
      #pragma unroll
      for (int n = 0; n < 4; ++n)
        Y[(i64)(b * 256 + o) * NPIX + pxbase + i0 + ih * 64 + n * 16 + fr] =
            acc[m][n][r] + bv;
    }
}

// ---------------------------------------------------------------------------
extern "C" void kernel_launch(void* const* d_in, const int* in_sizes, int n_in,
                              void* d_out, int out_size, void* d_ws, size_t ws_size,
                              hipStream_t stream) {
  const float* fmap = (const float*)d_in[0];
  const float* Wq   = (const float*)d_in[1];
  const float* Wdw  = (const float*)d_in[2];
  const float* Wpw  = (const float*)d_in[3];
  const float* Wout = (const float*)d_in[4];
  const float* bout = (const float*)d_in[5];
  float* out = (float*)d_out;
  short* dwh = (short*)d_out;   // d_out hosts dw fp16 (32MB; dead before wout)

  // ws layout (bytes), phase-aliased big region:
  //   wh       [0,       1048576)
  //   s_part   [1048576, 1572864)
  //   ctxh     [1572864, 2621440)
  //   BIG      [2621440, ...):
  //     phase1: ctx_part [2621440, 19398656)  (8.4 MB used)
  //             dwT      [19398656, 52953088) (33.5 MB)
  //     phase2: fmapT    [2621440, +33.5MB/S)
  //             out2     [..,      +67MB/S)
  char* ws = (char*)d_ws;
  short* wh       = (short*)(ws);
  float* s_part   = (float*)(ws + 1048576);
  short* ctxh     = (short*)(ws + 1572864);
  float* ctx_part = (float*)(ws + 2621440);
  short* dwT      = (short*)(ws + 19398656);

  i64 avail = (i64)ws_size - 2621440;
  const int S = (avail >= 100663296) ? 1 : 2;
  const int NS = NPIX / S;
  short* fmapT = (short*)(ws + 2621440);
  short* out2  = fmapT + (i64)16 * NS * 256;

  dwconv_kernel<<<16384, 256, 0, stream>>>(fmap, Wdw, dwh);
  wprep_kernel<<<2048, 256, 0, stream>>>(Wq, Wpw, Wout, wh);
  tcvt16_kernel<<<dim3(16, 4, 16), 256, 0, stream>>>(dwh, dwT);
  ctx_kernel<<<dim3(4, 8, 16), 256, 0, stream>>>(wh, dwT, ctx_part, s_part);
  merge_kernel<<<128, 256, 0, stream>>>(ctx_part, s_part, ctxh);
  for (int s = 0; s < S; ++s) {
    tcvt_kernel<<<dim3(NS / 256, 4, 16), 256, 0, stream>>>(fmap, fmapT, s * NS, NS);
    qpv_kernel<<<dim3(NS / 128, 8, 16), 256, 0, stream>>>(wh, fmapT, ctxh, out2, NS);
    wout_kernel<<<dim3(NS / 128, 4, 16), 256, 0, stream>>>(wh, out2, bout, out, s * NS, NS);
  }
}